// Round 10
// baseline (512.495 us; speedup 1.0000x reference)
//
#include <hip/hip_runtime.h>
#include <hip/hip_bf16.h>

typedef __hip_bfloat16 bf16t;
typedef short short8 __attribute__((ext_vector_type(8)));
typedef short short4v __attribute__((ext_vector_type(4)));
typedef float f32x4 __attribute__((ext_vector_type(4)));

// B=4, S=1024, D=1024, H=16, E=64, N=32 slots; tokens T=4096; slot-rows TS=131072
// Inputs/outputs are FLOAT32 (per reference). Internal activations bf16 for MFMA.

// fast native exp/rcp for throughput-bound epilogues (outputs round to bf16).
__device__ __forceinline__ float featf(float x) { return x > 0.f ? x + 1.f : __expf(x); }
// libm-exp variant for slot_all_k ONLY: measured 110us vs 122us with __expf there
// (latency-bound kernel; the longer libm sequence + its regalloc footprint wins).
__device__ __forceinline__ float featf_s(float x) { return x > 0.f ? x + 1.f : expf(x); }
__device__ __forceinline__ float frcp(float x) { return __builtin_amdgcn_rcpf(x); }
__device__ __forceinline__ float ldf(const bf16t* p, size_t i) { return __bfloat162float(p[i]); }
__device__ __forceinline__ float ldf(const float* p, size_t i) { return p[i]; }
__device__ __forceinline__ void stf(bf16t* p, size_t i, float v) { p[i] = __float2bfloat16(v); }
__device__ __forceinline__ void stf(float* p, size_t i, float v) { p[i] = v; }
__device__ __forceinline__ float b2f(unsigned short u) {
    unsigned int x = ((unsigned int)u) << 16; float f; __builtin_memcpy(&f, &x, 4); return f;
}
__device__ __forceinline__ unsigned short f2b(float f) {
    bf16t h = __float2bfloat16(f); unsigned short u; __builtin_memcpy(&u, &h, 2); return u;
}
// async global->LDS, 16B per lane; lds dest = wave-uniform base + lane*16
__device__ __forceinline__ void gl_lds16(const short* g, short* l) {
    __builtin_amdgcn_global_load_lds((const __attribute__((address_space(1))) unsigned int*)g,
                                     (__attribute__((address_space(3))) unsigned int*)l, 16, 0, 0);
}
#define MFMA16(a, b, c) __builtin_amdgcn_mfma_f32_16x16x32_bf16((a), (b), (c), 0, 0, 0)

// ---------------- sentinel fill (ws too small diagnostic) ----------------
__global__ __launch_bounds__(256) void fill_k(float* __restrict__ out, int n, float v) {
    int i = blockIdx.x * 256 + threadIdx.x;
    if (i < n) out[i] = v;
}

// ---------------- device helpers shared by merged kernels ----------------
// 32x32 tile transpose + fp32->bf16 (whole block takes same branch; barrier safe)
__device__ __forceinline__ void dev_transpose32(bf16t (*tile)[33], const float* W, bf16t* Wt,
                                                int R, int C, int lb) {
    int tiles_c = C >> 5;
    int c0 = (lb % tiles_c) * 32, r0 = (lb / tiles_c) * 32;
    int tx = threadIdx.x & 31, ty = threadIdx.x >> 5;  // 32 x 8
    #pragma unroll
    for (int i = 0; i < 32; i += 8)
        tile[ty + i][tx] = __float2bfloat16(W[(size_t)(r0 + ty + i) * C + (c0 + tx)]);
    __syncthreads();
    #pragma unroll
    for (int i = 0; i < 32; i += 8)
        Wt[(size_t)(c0 + ty + i) * R + (r0 + tx)] = tile[tx][ty + i];
}

// LayerNorm over D=1024 (fp32 in, bf16 out), one block per token t
__device__ __forceinline__ void dev_ln(float* rs, float* rq,
                                       const float* X, const float* g, const float* b,
                                       bf16t* Y, int t) {
    int tid = threadIdx.x;
    size_t base = (size_t)t * 1024 + tid * 4;
    float v0 = X[base + 0], v1 = X[base + 1], v2 = X[base + 2], v3 = X[base + 3];
    float s = v0 + v1 + v2 + v3;
    float q = v0 * v0 + v1 * v1 + v2 * v2 + v3 * v3;
    for (int o = 32; o > 0; o >>= 1) { s += __shfl_down(s, o); q += __shfl_down(q, o); }
    int wid = tid >> 6, lane = tid & 63;
    if (lane == 0) { rs[wid] = s; rq[wid] = q; }
    __syncthreads();
    float S = rs[0] + rs[1] + rs[2] + rs[3];
    float Q = rq[0] + rq[1] + rq[2] + rq[3];
    float mean = S * (1.f / 1024.f);
    float var = Q * (1.f / 1024.f) - mean * mean;
    float rstd = rsqrtf(var + 1e-5f);
    int c = tid * 4;
    stf(Y, base + 0, (v0 - mean) * rstd * g[c + 0] + b[c + 0]);
    stf(Y, base + 1, (v1 - mean) * rstd * g[c + 1] + b[c + 1]);
    stf(Y, base + 2, (v2 - mean) * rstd * g[c + 2] + b[c + 2]);
    stf(Y, base + 3, (v3 - mean) * rstd * g[c + 3] + b[c + 3]);
}

// ---------------- standalone LN (for LN2; depends on Wf GEMM so can't merge) ----------------
__global__ __launch_bounds__(256) void ln_kernel(const float* __restrict__ X,
                                                 const float* __restrict__ g,
                                                 const float* __restrict__ b,
                                                 bf16t* __restrict__ Y) {
    __shared__ float rs[4], rq[4];
    dev_ln(rs, rq, X, g, b, Y, blockIdx.x);
}

// ======= STAGE1: small_prep + LN1 + projection-weight transposes in ONE launch ===========
// blocks [0,5120): transpose [Wk|Wv|Wip|Wq] -> Wcat; [5120,9216): LN1; [9216,9223): prep.
__global__ __launch_bounds__(256) void stage1_k(const float* __restrict__ x,
                                                const float* __restrict__ ln1g,
                                                const float* __restrict__ ln1b,
                                                bf16t* __restrict__ xn,
                                                const float* __restrict__ Wk,
                                                const float* __restrict__ Wv,
                                                const float* __restrict__ Wip,
                                                const float* __restrict__ Wq,
                                                bf16t* __restrict__ Wcat,
                                                const float* __restrict__ Wtk,
                                                const float* __restrict__ Wtv,
                                                const float* __restrict__ Wtq,
                                                const float* __restrict__ Wl1,
                                                const float* __restrict__ Wl2,
                                                const float* __restrict__ Wsp,
                                                const float* __restrict__ bk,
                                                const float* __restrict__ bv,
                                                const float* __restrict__ bip,
                                                const float* __restrict__ bq,
                                                const float* __restrict__ btk,
                                                const float* __restrict__ btv,
                                                bf16t* __restrict__ WtkvT,
                                                bf16t* __restrict__ WtqI,
                                                bf16t* __restrict__ Wl1T,
                                                bf16t* __restrict__ Wl2T,
                                                bf16t* __restrict__ WspT,
                                                float* __restrict__ bcat,
                                                float* __restrict__ bcat2) {
    __shared__ bf16t tile[32][33];
    __shared__ float rs[4], rq[4];
    int b = blockIdx.x, tid = threadIdx.x;
    if (b < 5120) {
        // 4-job transpose: rows [Wk | Wv | Wip | Wq] into Wcat
        const float* W; bf16t* Wt; int R, C, lb;
        if (b < 1024)      { W = Wk;  Wt = Wcat;                          R = 1024; C = 1024; lb = b; }
        else if (b < 2048) { W = Wv;  Wt = Wcat + (size_t)1024 * 1024;    R = 1024; C = 1024; lb = b - 1024; }
        else if (b < 4096) { W = Wip; Wt = Wcat + (size_t)2048 * 1024;    R = 1024; C = 2048; lb = b - 2048; }
        else               { W = Wq;  Wt = Wcat + (size_t)4096 * 1024;    R = 1024; C = 1024; lb = b - 4096; }
        dev_transpose32(tile, W, Wt, R, C, lb);
    } else if (b < 9216) {
        dev_ln(rs, rq, x, ln1g, ln1b, xn, b - 5120);
    } else {
        int pb = b - 9216;
        if (pb == 0) {
            for (int i = tid; i < 8192; i += 256) {
                int n2 = i >> 6, e = i & 63;
                float v = (n2 < 64) ? Wtk[e * 64 + n2] : Wtv[e * 64 + (n2 - 64)];
                WtkvT[i] = __float2bfloat16(v);
            }
        } else if (pb == 1) {
            for (int i = tid; i < 8192; i += 256) {
                int e = i >> 7, k = i & 127;
                float v = (k < 64) ? Wtq[k * 64 + e] : ((k - 64 == e) ? 1.f : 0.f);
                WtqI[i] = __float2bfloat16(v);
            }
        } else if (pb == 2) {
            for (int i = tid; i < 8192; i += 256) { int n = i >> 6, k = i & 63; Wl1T[i] = __float2bfloat16(Wl1[k * 128 + n]); }
        } else if (pb == 3) {
            for (int i = tid; i < 8192; i += 256) { int n = i >> 7, k = i & 127; Wl2T[i] = __float2bfloat16(Wl2[k * 64 + n]); }
        } else if (pb == 4) {
            for (int i = tid; i < 8192; i += 256) { int n = i >> 7, k = i & 127; WspT[i] = __float2bfloat16(Wsp[k * 64 + n]); }
        } else if (pb == 5) {
            for (int i = tid; i < 5120; i += 256) {
                float v;
                if (i < 1024) v = bk[i];
                else if (i < 2048) v = bv[i - 1024];
                else if (i < 4096) v = bip[i - 2048];
                else v = bq[i - 4096];
                bcat[i] = v;
            }
        } else {
            if (tid < 128) bcat2[tid] = (tid < 64) ? btk[tid] : btv[tid - 64];
        }
    }
}

// ======= 64x128-tile MFMA GEMM, BK=64 (halved barrier count): Wr1 =======================
// Each of 4 waves: 64 rows x 32 cols (acc[4][2]); per K-step 6 gl_lds16 + 16 MFMAs.
// LDS 24KB. MODE 0: v  4: relu(v)  5: v+add. XCD-chunked bid (grid %8==0).
template <int MODE, typename TC, typename TADD>
__global__ __launch_bounds__(256) void gemm64_k(const bf16t* __restrict__ A,
                                                const bf16t* __restrict__ Bt,
                                                const float* __restrict__ bias,
                                                const TADD* __restrict__ add,
                                                TC* __restrict__ C,
                                                int M, int N, int K, int ldC) {
    __shared__ short As[64 * 64];
    __shared__ short Bs[128 * 64];
    int tid = threadIdx.x;
    int wave = tid >> 6, lane = tid & 63;
    int l16 = lane & 15, quad = lane >> 4;
    int tilesM = M >> 6;
    int bid = (blockIdx.x & 7) * (gridDim.x >> 3) + (blockIdx.x >> 3);  // XCD-chunked
    int tm = bid % tilesM;           // column-major: consecutive bids share the B panel
    int tn = bid / tilesM;

    int lrow8 = lane >> 3;           // 0..7 (row within 8-row stripe; 64-col rows = 128B)
    int lseg8 = (lane & 7) * 8;      // 0..56
    const short* Ag  = (const short*)A + (size_t)(tm * 64 + wave * 16 + lrow8) * K + lseg8;
    const short* Ag2 = Ag + (size_t)8 * K;
    const short* Bg  = (const short*)Bt + (size_t)(tn * 128 + wave * 32 + lrow8) * K + lseg8;
    const short* Bg2 = Bg + (size_t)8 * K;
    const short* Bg3 = Bg + (size_t)16 * K;
    const short* Bg4 = Bg + (size_t)24 * K;
    short* Asw  = As + (wave * 16) * 64;
    short* Asw2 = Asw + 8 * 64;
    short* Bsw  = Bs + (wave * 32) * 64;
    short* Bsw2 = Bsw + 8 * 64;
    short* Bsw3 = Bsw + 16 * 64;
    short* Bsw4 = Bsw + 24 * 64;

    f32x4 acc[4][2] = {};
    for (int k0 = 0; k0 < K; k0 += 64) {
        gl_lds16(Ag + k0, Asw);
        gl_lds16(Ag2 + k0, Asw2);
        gl_lds16(Bg + k0, Bsw);
        gl_lds16(Bg2 + k0, Bsw2);
        gl_lds16(Bg3 + k0, Bsw3);
        gl_lds16(Bg4 + k0, Bsw4);
        __syncthreads();
        #pragma unroll
        for (int kk = 0; kk < 2; kk++) {
            short8 av[4], bv[2];
            #pragma unroll
            for (int i = 0; i < 4; i++)
                av[i] = *(const short8*)(As + (i * 16 + l16) * 64 + kk * 32 + quad * 8);
            #pragma unroll
            for (int j = 0; j < 2; j++)
                bv[j] = *(const short8*)(Bs + (wave * 32 + j * 16 + l16) * 64 + kk * 32 + quad * 8);
            #pragma unroll
            for (int i = 0; i < 4; i++)
                #pragma unroll
                for (int j = 0; j < 2; j++)
                    acc[i][j] = MFMA16(av[i], bv[j], acc[i][j]);
        }
        __syncthreads();
    }

    #pragma unroll
    for (int j = 0; j < 2; j++) {
        int col = tn * 128 + wave * 32 + j * 16 + l16;
        float bcol = bias[col];
        #pragma unroll
        for (int i = 0; i < 4; i++) {
            int row0 = tm * 64 + i * 16 + quad * 4;
            #pragma unroll
            for (int r = 0; r < 4; r++) {
                int row = row0 + r;
                float v = acc[i][j][r] + bcol;
                float outv;
                if constexpr (MODE == 0) outv = v;
                else if constexpr (MODE == 4) outv = fmaxf(v, 0.f);
                else if constexpr (MODE == 5) outv = v + ldf(add, (size_t)row * N + col);
                else outv = v;
                stf(C, (size_t)row * ldC + col, outv);
            }
        }
    }
}

// ======= 64x64-tile MFMA GEMM, BK=64: Wf, Wr2 (4 blocks/CU at these shapes) ==============
// Each of 4 waves: 64 rows x 16 cols (acc[4]); per K-step 4 gl_lds16 + 8 MFMAs. LDS 16KB.
template <int MODE, typename TC, typename TADD>
__global__ __launch_bounds__(256) void gemm6464_k(const bf16t* __restrict__ A,
                                                  const bf16t* __restrict__ Bt,
                                                  const float* __restrict__ bias,
                                                  const TADD* __restrict__ add,
                                                  TC* __restrict__ C,
                                                  int M, int N, int K, int ldC) {
    __shared__ short As[64 * 64];
    __shared__ short Bs[64 * 64];
    int tid = threadIdx.x;
    int wave = tid >> 6, lane = tid & 63;
    int l16 = lane & 15, quad = lane >> 4;
    int tilesM = M >> 6;
    int bid = (blockIdx.x & 7) * (gridDim.x >> 3) + (blockIdx.x >> 3);  // XCD-chunked
    int tm = bid % tilesM;           // column-major: consecutive bids share the B panel
    int tn = bid / tilesM;

    int lrow8 = lane >> 3;
    int lseg8 = (lane & 7) * 8;
    const short* Ag  = (const short*)A + (size_t)(tm * 64 + wave * 16 + lrow8) * K + lseg8;
    const short* Ag2 = Ag + (size_t)8 * K;
    const short* Bg  = (const short*)Bt + (size_t)(tn * 64 + wave * 16 + lrow8) * K + lseg8;
    const short* Bg2 = Bg + (size_t)8 * K;
    short* Asw  = As + (wave * 16) * 64;
    short* Asw2 = Asw + 8 * 64;
    short* Bsw  = Bs + (wave * 16) * 64;
    short* Bsw2 = Bsw + 8 * 64;

    f32x4 acc[4] = {};
    for (int k0 = 0; k0 < K; k0 += 64) {
        gl_lds16(Ag + k0, Asw);
        gl_lds16(Ag2 + k0, Asw2);
        gl_lds16(Bg + k0, Bsw);
        gl_lds16(Bg2 + k0, Bsw2);
        __syncthreads();
        #pragma unroll
        for (int kk = 0; kk < 2; kk++) {
            short8 av[4], bv;
            #pragma unroll
            for (int i = 0; i < 4; i++)
                av[i] = *(const short8*)(As + (i * 16 + l16) * 64 + kk * 32 + quad * 8);
            bv = *(const short8*)(Bs + (wave * 16 + l16) * 64 + kk * 32 + quad * 8);
            #pragma unroll
            for (int i = 0; i < 4; i++)
                acc[i] = MFMA16(av[i], bv, acc[i]);
        }
        __syncthreads();
    }

    {
        int col = tn * 64 + wave * 16 + l16;
        float bcol = bias[col];
        #pragma unroll
        for (int i = 0; i < 4; i++) {
            int row0 = tm * 64 + i * 16 + quad * 4;
            #pragma unroll
            for (int r = 0; r < 4; r++) {
                int row = row0 + r;
                float v = acc[i][r] + bcol;
                float outv;
                if constexpr (MODE == 0) outv = v;
                else if constexpr (MODE == 4) outv = fmaxf(v, 0.f);
                else if constexpr (MODE == 5) outv = v + ldf(add, (size_t)row * N + col);
                else outv = v;
                stf(C, (size_t)row * ldC + col, outv);
            }
        }
    }
}

// ======= merged projection GEMM: [xn] @ [Wk|Wv|Wip|Wq]^T (N=5120), split epilogue =========
__global__ __launch_bounds__(256) void gemm_proj_k(const bf16t* __restrict__ A,
                                                   const bf16t* __restrict__ Bt,
                                                   const float* __restrict__ bias,
                                                   bf16t* __restrict__ kv0,
                                                   bf16t* __restrict__ inp,
                                                   bf16t* __restrict__ qf) {
    __shared__ short As[128 * 32];
    __shared__ short Bs[128 * 32];
    const int K = 1024;
    int tid = threadIdx.x;
    int wave = tid >> 6, lane = tid & 63;
    int l16 = lane & 15, quad = lane >> 4;
    int bid = (blockIdx.x & 7) * (gridDim.x >> 3) + (blockIdx.x >> 3);  // XCD-chunked (1280%8==0)
    int tm = bid & 31;
    int tn = bid >> 5;
    int wm = wave >> 1, wn = wave & 1;

    int lrow = lane >> 2;
    int lseg = (lane & 3) * 8;
    const short* Ag = (const short*)A + (size_t)(tm * 128 + wave * 32 + lrow) * K + lseg;
    const short* Ag2 = Ag + (size_t)16 * K;
    const short* Bg = (const short*)Bt + (size_t)(tn * 128 + wave * 32 + lrow) * K + lseg;
    const short* Bg2 = Bg + (size_t)16 * K;
    short* Asw = As + (wave * 32) * 32;
    short* Asw2 = Asw + 16 * 32;
    short* Bsw = Bs + (wave * 32) * 32;
    short* Bsw2 = Bsw + 16 * 32;

    f32x4 acc[4][4] = {};
    for (int k0 = 0; k0 < K; k0 += 32) {
        gl_lds16(Ag + k0, Asw);
        gl_lds16(Ag2 + k0, Asw2);
        gl_lds16(Bg + k0, Bsw);
        gl_lds16(Bg2 + k0, Bsw2);
        __syncthreads();
        short8 av[4], bv[4];
        #pragma unroll
        for (int i = 0; i < 4; i++)
            av[i] = *(const short8*)(As + (wm * 64 + i * 16 + l16) * 32 + quad * 8);
        #pragma unroll
        for (int j = 0; j < 4; j++)
            bv[j] = *(const short8*)(Bs + (wn * 64 + j * 16 + l16) * 32 + quad * 8);
        #pragma unroll
        for (int i = 0; i < 4; i++)
            #pragma unroll
            for (int j = 0; j < 4; j++)
                acc[i][j] = MFMA16(av[i], bv[j], acc[i][j]);
        __syncthreads();
    }

    #pragma unroll
    for (int j = 0; j < 4; j++) {
        int col = tn * 128 + wn * 64 + j * 16 + l16;
        float bcol = bias[col];
        #pragma unroll
        for (int i = 0; i < 4; i++) {
            int row0 = tm * 128 + wm * 64 + i * 16 + quad * 4;
            #pragma unroll
            for (int r = 0; r < 4; r++) {
                int row = row0 + r;
                float v = acc[i][j][r] + bcol;
                if (tn < 16) stf(kv0, (size_t)row * 2048 + col, v);
                else if (tn < 32) stf(inp, (size_t)row * 2048 + (col - 2048), v);
                else stf(qf, (size_t)row * 1024 + (col - 4096), featf(v * 0.125f));
            }
        }
    }
}

// ------- merged kk/vvT GEMM: inp[TS,64] @ [WtkT|WtvT]^T; kk=feat, vvT transpose-store -------
__global__ __launch_bounds__(256) void gemm_kv_k(const bf16t* __restrict__ A,
                                                 const bf16t* __restrict__ Bt,
                                                 const float* __restrict__ bias,
                                                 bf16t* __restrict__ kkO,
                                                 bf16t* __restrict__ vvTO) {
    int wave = threadIdx.x >> 6, lane = threadIdx.x & 63;
    int tile = blockIdx.x * 4 + wave;        // 4096 tiles: 2048 m x 2 n
    int tm = tile >> 1, tn = tile & 1;
    int l16 = lane & 15, quad = lane >> 4;
    f32x4 acc[4][4] = {};
    const short* Ab = (const short*)A + (size_t)(tm * 64 + l16) * 64;
    const short* Bb = (const short*)Bt + (size_t)(tn * 64 + l16) * 64;
    #pragma unroll
    for (int k0 = 0; k0 < 64; k0 += 32) {
        int ka = k0 + quad * 8;
        short8 av[4], bv[4];
        #pragma unroll
        for (int i = 0; i < 4; i++) av[i] = *(const short8*)(Ab + (size_t)i * 16 * 64 + ka);
        #pragma unroll
        for (int j = 0; j < 4; j++) bv[j] = *(const short8*)(Bb + (size_t)j * 16 * 64 + ka);
        #pragma unroll
        for (int i = 0; i < 4; i++)
            #pragma unroll
            for (int j = 0; j < 4; j++)
                acc[i][j] = MFMA16(av[i], bv[j], acc[i][j]);
    }
    #pragma unroll
    for (int j = 0; j < 4; j++) {
        int col = j * 16 + l16;
        float bcol = bias[tn * 64 + col];
        #pragma unroll
        for (int i = 0; i < 4; i++) {
            int row0 = tm * 64 + i * 16 + quad * 4;
            #pragma unroll
            for (int r = 0; r < 4; r++) {
                int row = row0 + r;
                float v = acc[i][j][r] + bcol;
                if (tn == 0) kkO[(size_t)row * 64 + col] = __float2bfloat16(featf(v));
                else stf(vvTO, (size_t)(row >> 5) * 2048 + (size_t)col * 32 + (row & 31), v);
            }
        }
    }
}

// ---------------- fused concat GEMM: C[TS,64] = [A1|A2] @ Bt[64,128]^T + bias -------------
__global__ __launch_bounds__(256) void gemm_cat_k(const bf16t* __restrict__ A1,
                                                  const bf16t* __restrict__ A2,
                                                  const bf16t* __restrict__ Bt,
                                                  const float* __restrict__ bias,
                                                  bf16t* __restrict__ C, int M) {
    int wave = threadIdx.x >> 6;
    int lane = threadIdx.x & 63;
    int tiles = M >> 6;
    int tile = blockIdx.x * 4 + wave;
    if (tile >= tiles) return;
    int tm = tile;
    int l16 = lane & 15, quad = lane >> 4;
    f32x4 acc[4][4] = {};
    #pragma unroll
    for (int p = 0; p < 2; p++) {
        const short* Ab = (const short*)(p ? A2 : A1) + (size_t)(tm * 64 + l16) * 64;
        const short* Bb = (const short*)Bt + (size_t)l16 * 128 + p * 64;
        #pragma unroll
        for (int k0 = 0; k0 < 64; k0 += 32) {
            int ka = k0 + quad * 8;
            short8 av[4], bv[4];
            #pragma unroll
            for (int i = 0; i < 4; i++) av[i] = *(const short8*)(Ab + (size_t)i * 16 * 64 + ka);
            #pragma unroll
            for (int j = 0; j < 4; j++) bv[j] = *(const short8*)(Bb + (size_t)j * 16 * 128 + ka);
            #pragma unroll
            for (int i = 0; i < 4; i++)
                #pragma unroll
                for (int j = 0; j < 4; j++)
                    acc[i][j] = MFMA16(av[i], bv[j], acc[i][j]);
        }
    }
    #pragma unroll
    for (int j = 0; j < 4; j++) {
        int col = j * 16 + l16;
        float bcol = bias[col];
        #pragma unroll
        for (int i = 0; i < 4; i++) {
            int row0 = tm * 64 + i * 16 + quad * 4;
            #pragma unroll
            for (int r = 0; r < 4; r++)
                C[(size_t)(row0 + r) * 64 + col] = __float2bfloat16(acc[i][j][r] + bcol);
        }
    }
}

// ========== fused slot loop: all 3 iterations, one wave per token, MFMA throughout =========
// BASELINE version (109-112us @ 124 VGPR measured; empirical floor over 6 experiments):
// libm expf, real fp divides, pitch-72 LDS, shfl-max softmax, no setprio, no bounds cap.
// History: __expf/frcp diet -> 122us@108 (R1); +swizzle/const-shift -> 162us@140 (R3);
// +launch_bounds(256,4) -> 64 VGPR + scratch spills, 215us (R4). DO NOT touch without
// a within-probe A/B and -Rpass-analysis register check.
__global__ __launch_bounds__(256) void slot_all_k(const bf16t* __restrict__ kv0,
                                                  const bf16t* __restrict__ kk,
                                                  const bf16t* __restrict__ vvT,
                                                  const bf16t* __restrict__ WtqI,
                                                  const float* __restrict__ btq,
                                                  const float* __restrict__ lnpg,
                                                  const float* __restrict__ lnpb,
                                                  const bf16t* __restrict__ Wl1T,
                                                  const float* __restrict__ bl1,
                                                  const bf16t* __restrict__ Wl2T,
                                                  const float* __restrict__ bl2,
                                                  bf16t* __restrict__ slots_out,
                                                  int zoff) {
    __shared__ short slotsS[4][32 * 72];   // per-wave slots [n][e] pitch 72
    __shared__ short scratch[4][32 * 72];  // per-wave qq/attnT/hln/h1-chunk
    int wave = threadIdx.x >> 6, lane = threadIdx.x & 63;
    int l16 = lane & 15, quad = lane >> 4;
    int t = blockIdx.x * 4 + wave;
    short* S = slotsS[wave];
    short* X = scratch[wave];
    size_t tbase = (size_t)t * 2048;

    // slots := kv0 (vectorized copy to LDS, pitch 72)
    {
        const short* src = (const short*)kv0 + tbase;
        #pragma unroll
        for (int p = 0; p < 4; p++) {
            int idx = p * 512 + lane * 8;
            int row = idx >> 6, col = idx & 63;
            *(short8*)(S + row * 72 + col) = *(const short8*)(src + idx);
        }
    }

    #pragma unroll 1
    for (int it = 0; it < 3; it++) {
        int vo = it * zoff;   // zoff==0 at runtime; symbolic per-iteration offset
        // ---- qq = feat(([slots|kv0] @ WtqI^T + btq)/8) -> X [n][e] pitch 72
        f32x4 aq[2][4] = {};
        #pragma unroll
        for (int k0 = 0; k0 < 4; k0++) {
            short8 af[2];
            #pragma unroll
            for (int i = 0; i < 2; i++) {
                if (k0 < 2)
                    af[i] = *(const short8*)(S + (i * 16 + l16) * 72 + k0 * 32 + quad * 8);
                else
                    af[i] = *(const short8*)((const short*)kv0 + tbase + (size_t)((i * 16 + l16) * 64 + (k0 - 2) * 32 + quad * 8 + vo));
            }
            #pragma unroll
            for (int j = 0; j < 4; j++) {
                short8 bf_ = *(const short8*)((const short*)WtqI + (size_t)((j * 16 + l16) * 128 + k0 * 32 + quad * 8 + vo));
                #pragma unroll
                for (int i = 0; i < 2; i++) aq[i][j] = MFMA16(af[i], bf_, aq[i][j]);
            }
        }
        {
            float btqv[4];
            #pragma unroll
            for (int j = 0; j < 4; j++) btqv[j] = btq[j * 16 + l16 + vo];
            #pragma unroll
            for (int i = 0; i < 2; i++)
                #pragma unroll
                for (int j = 0; j < 4; j++)
                    #pragma unroll
                    for (int r = 0; r < 4; r++) {
                        int n = i * 16 + quad * 4 + r, e = j * 16 + l16;
                        X[n * 72 + e] = (short)f2b(featf_s((aq[i][j][r] + btqv[j]) * 0.125f));
                    }
        }
        // ---- logits[w][n] = kk @ qq^T
        f32x4 al[2][2] = {};
        #pragma unroll
        for (int k0 = 0; k0 < 2; k0++) {
            short8 ak[2], bf_[2];
            #pragma unroll
            for (int i = 0; i < 2; i++)
                ak[i] = *(const short8*)((const short*)kk + tbase + (size_t)((i * 16 + l16) * 64 + k0 * 32 + quad * 8 + vo));
            #pragma unroll
            for (int j = 0; j < 2; j++)
                bf_[j] = *(const short8*)(X + (j * 16 + l16) * 72 + k0 * 32 + quad * 8);
            #pragma unroll
            for (int i = 0; i < 2; i++)
                #pragma unroll
                for (int j = 0; j < 2; j++)
                    al[i][j] = MFMA16(ak[i], bf_[j], al[i][j]);
        }
        // ---- softmax over n (rows w), normalize over w (cols n)
        #pragma unroll
        for (int i = 0; i < 2; i++)
            #pragma unroll
            for (int r = 0; r < 4; r++) {
                float m = fmaxf(al[i][0][r], al[i][1][r]);
                #pragma unroll
                for (int d = 1; d < 16; d <<= 1) m = fmaxf(m, __shfl_xor(m, d));
                float e0 = expf(al[i][0][r] - m), e1 = expf(al[i][1][r] - m);
                float s = e0 + e1;
                #pragma unroll
                for (int d = 1; d < 16; d <<= 1) s += __shfl_xor(s, d);
                float inv = 1.f / s;
                al[i][0][r] = e0 * inv + 1e-6f;
                al[i][1][r] = e1 * inv + 1e-6f;
            }
        #pragma unroll
        for (int j = 0; j < 2; j++) {
            float cs = 0.f;
            #pragma unroll
            for (int i = 0; i < 2; i++)
                #pragma unroll
                for (int r = 0; r < 4; r++) cs += al[i][j][r];
            cs += __shfl_xor(cs, 16);
            cs += __shfl_xor(cs, 32);
            float inv = 1.f / cs;
            #pragma unroll
            for (int i = 0; i < 2; i++)
                #pragma unroll
                for (int r = 0; r < 4; r++) al[i][j][r] *= inv;
        }
        // ---- attn^T -> X [n][w] pitch 40
        #pragma unroll
        for (int i = 0; i < 2; i++)
            #pragma unroll
            for (int j = 0; j < 2; j++)
                #pragma unroll
                for (int r = 0; r < 4; r++) {
                    int w = i * 16 + quad * 4 + r, n = j * 16 + l16;
                    X[n * 40 + w] = (short)f2b(al[i][j][r]);
                }
        // ---- upd[n][e] = attnT @ vvT
        f32x4 au[2][4] = {};
        {
            short8 af[2];
            #pragma unroll
            for (int i = 0; i < 2; i++)
                af[i] = *(const short8*)(X + (i * 16 + l16) * 40 + quad * 8);
            #pragma unroll
            for (int j = 0; j < 4; j++) {
                short8 bf_ = *(const short8*)((const short*)vvT + tbase + (size_t)((j * 16 + l16) * 32 + quad * 8 + vo));
                #pragma unroll
                for (int i = 0; i < 2; i++) au[i][j] = MFMA16(af[i], bf_, au[i][j]);
            }
        }
        // ---- LN over e per row n -> X [n][e] pitch 72
        {
            float lgv[4], lbv[4];
            #pragma unroll
            for (int j = 0; j < 4; j++) { lgv[j] = lnpg[j * 16 + l16 + vo]; lbv[j] = lnpb[j * 16 + l16 + vo]; }
            #pragma unroll
            for (int i = 0; i < 2; i++)
                #pragma unroll
                for (int r = 0; r < 4; r++) {
                    float s1 = 0.f, s2 = 0.f;
                    #pragma unroll
                    for (int j = 0; j < 4; j++) { float u = au[i][j][r]; s1 += u; s2 += u * u; }
                    #pragma unroll
                    for (int d = 1; d < 16; d <<= 1) { s1 += __shfl_xor(s1, d); s2 += __shfl_xor(s2, d); }
                    float mean = s1 * (1.f / 64.f);
                    float var = s2 * (1.f / 64.f) - mean * mean;
                    float rstd = rsqrtf(var + 1e-5f);
                    int n = i * 16 + quad * 4 + r;
                    #pragma unroll
                    for (int j = 0; j < 4; j++)
                        X[n * 72 + j * 16 + l16] = (short)f2b((au[i][j][r] - mean) * rstd * lgv[j] + lbv[j]);
                }
        }
        // ---- MLP (chunked): preload hln A-frags, then 2 chunks of 64 h1-cols
        short8 a1[2][2];
        #pragma unroll
        for (int i = 0; i < 2; i++)
            #pragma unroll
            for (int k0 = 0; k0 < 2; k0++)
                a1[i][k0] = *(const short8*)(X + (i * 16 + l16) * 72 + k0 * 32 + quad * 8);
        f32x4 ac2[2][4] = {};
        #pragma unroll
        for (int c = 0; c < 2; c++) {
            f32x4 ac1[2][4] = {};
            #pragma unroll
            for (int k0 = 0; k0 < 2; k0++)
                #pragma unroll
                for (int j = 0; j < 4; j++) {
                    short8 bf_ = *(const short8*)((const short*)Wl1T + (size_t)(((c * 4 + j) * 16 + l16) * 64 + k0 * 32 + quad * 8 + vo));
                    #pragma unroll
                    for (int i = 0; i < 2; i++) ac1[i][j] = MFMA16(a1[i][k0], bf_, ac1[i][j]);
                }
            {
                float bl1v[4];
                #pragma unroll
                for (int j = 0; j < 4; j++) bl1v[j] = bl1[(c * 4 + j) * 16 + l16 + vo];
                #pragma unroll
                for (int i = 0; i < 2; i++)
                    #pragma unroll
                    for (int j = 0; j < 4; j++)
                        #pragma unroll
                        for (int r = 0; r < 4; r++) {
                            int n = i * 16 + quad * 4 + r;
                            X[n * 72 + j * 16 + l16] = (short)f2b(fmaxf(ac1[i][j][r] + bl1v[j], 0.f));
                        }
            }
            #pragma unroll
            for (int kc = 0; kc < 2; kc++) {
                short8 a2[2];
                #pragma unroll
                for (int i = 0; i < 2; i++)
                    a2[i] = *(const short8*)(X + (i * 16 + l16) * 72 + kc * 32 + quad * 8);
                int k1 = c * 2 + kc;
                #pragma unroll
                for (int j = 0; j < 4; j++) {
                    short8 bf_ = *(const short8*)((const short*)Wl2T + (size_t)((j * 16 + l16) * 128 + k1 * 32 + quad * 8 + vo));
                    #pragma unroll
                    for (int i = 0; i < 2; i++) ac2[i][j] = MFMA16(a2[i], bf_, ac2[i][j]);
                }
            }
        }
        // ---- slot update
        {
            float bl2v[4];
            #pragma unroll
            for (int j = 0; j < 4; j++) bl2v[j] = bl2[j * 16 + l16 + vo];
            #pragma unroll
            for (int i = 0; i < 2; i++)
                #pragma unroll
                for (int j = 0; j < 4; j++)
                    #pragma unroll
                    for (int r = 0; r < 4; r++) {
                        int n = i * 16 + quad * 4 + r, e = j * 16 + l16;
                        float old = b2f((unsigned short)S[n * 72 + e]);
                        S[n * 72 + e] = (short)f2b(old + (ac2[i][j][r] + bl2v[j]) * (1.f / 64.f));
                    }
        }
    }
    // write final slots
    {
        short* dst = (short*)slots_out + tbase;
        #pragma unroll
        for (int p = 0; p < 4; p++) {
            int idx = p * 512 + lane * 8;
            int row = idx >> 6, col = idx & 63;
            *(short8*)(dst + idx) = *(const short8*)(S + row * 72 + col);
        }
    }
}

// ======= TAIL MIX: kv_outer (256 blocks, critical path first) + tail weight transposes ====
// Both legal right after gemm_cat: R_kv0 is dead (transposes overlay it), slotsO ready.
__global__ __launch_bounds__(256) void tail_mix_k(const bf16t* __restrict__ slotsO,
                                                  float* __restrict__ Kpart,
                                                  float* __restrict__ kspart,
                                                  const float* __restrict__ Wf,
                                                  const float* __restrict__ Wr1,
                                                  const float* __restrict__ Wr2,
                                                  bf16t* __restrict__ WfT,
                                                  bf16t* __restrict__ Wr1T,
                                                  bf16t* __restrict__ Wr2T) {
    __shared__ short kfT[64 * 72];   // [e][s] pitch 72
    __shared__ short v2T[64 * 72];   // [vj][s] pitch 72
    __shared__ float ksred[8][64];
    __shared__ bf16t tile[32][33];
    int gb = blockIdx.x;
    if (gb >= 256) {
        int lb = gb - 256;
        const float* W; bf16t* Wt; int R, C;
        if (lb < 1024)      { W = Wf;  Wt = WfT;  R = 1024; C = 1024; }
        else if (lb < 3072) { W = Wr1; Wt = Wr1T; R = 1024; C = 2048; lb -= 1024; }
        else                { W = Wr2; Wt = Wr2T; R = 2048; C = 1024; lb -= 3072; }
        dev_transpose32(tile, W, Wt, R, C, lb);
        return;
    }
    // ---- kv_outer: Kpart[vj][e] over a 256-row s-chunk; kspart partial sum_s kf ----
    int blk = gb;
    int bh = blk >> 2, chunk = blk & 3;
    int b = bh >> 4, h = bh & 15;
    int tid = threadIdx.x;
    int wave = tid >> 6, lane = tid & 63;
    int l16 = lane & 15, quad = lane >> 4;
    int m0 = wave * 16;

    int sgrp = tid >> 5;
    int e0 = (tid & 31) * 2;
    float ks0 = 0.f, ks1 = 0.f;
    f32x4 acc[4];
    #pragma unroll
    for (int j = 0; j < 4; j++) acc[j] = (f32x4){0.f, 0.f, 0.f, 0.f};

    for (int tile2 = chunk * 4; tile2 < chunk * 4 + 4; tile2++) {
        #pragma unroll
        for (int p = 0; p < 8; p++) {
            int sl = p * 8 + sgrp;
            size_t row = ((size_t)(b * 1024 + tile2 * 64 + sl)) * 2048;
            unsigned int dk = *(const unsigned int*)((const unsigned short*)slotsO + row + h * 64 + e0);
            float f0 = featf(b2f((unsigned short)(dk & 0xffff)));
            float f1 = featf(b2f((unsigned short)(dk >> 16)));
            ks0 += f0; ks1 += f1;
            kfT[e0 * 72 + sl] = (short)f2b(f0);
            kfT[(e0 + 1) * 72 + sl] = (short)f2b(f1);
            unsigned int dv = *(const unsigned int*)((const unsigned short*)slotsO + row + (16 + h) * 64 + e0);
            v2T[e0 * 72 + sl] = (short)(dv & 0xffff);
            v2T[(e0 + 1) * 72 + sl] = (short)(dv >> 16);
        }
        __syncthreads();
        #pragma unroll
        for (int k2 = 0; k2 < 2; k2++) {
            short8 a = *(const short8*)(v2T + (m0 + l16) * 72 + k2 * 32 + quad * 8);
            #pragma unroll
            for (int j = 0; j < 4; j++) {
                short8 bv = *(const short8*)(kfT + (j * 16 + l16) * 72 + k2 * 32 + quad * 8);
                acc[j] = MFMA16(a, bv, acc[j]);
            }
        }
        __syncthreads();
    }

    float* Km = Kpart + (size_t)blk * 4096;
    #pragma unroll
    for (int j = 0; j < 4; j++)
        #pragma unroll
        for (int r = 0; r < 4; r++)
            Km[(m0 + quad * 4 + r) * 64 + j * 16 + l16] = acc[j][r];

    ksred[sgrp][e0] = ks0;
    ksred[sgrp][e0 + 1] = ks1;
    __syncthreads();
    if (tid < 64) {
        float s = 0.f;
        #pragma unroll
        for (int r = 0; r < 8; r++) s += ksred[r][tid];
        kspart[blk * 64 + tid] = s;
    }
}

// ------- reduce 4 Kpart chunks -> bf16 KmatT[bh][vj][e]; kspart -> f32 ksum ----------------
__global__ __launch_bounds__(256) void kred_k(const float* __restrict__ Kpart,
                                              const float* __restrict__ kspart,
                                              bf16t* __restrict__ KmatT,
                                              float* __restrict__ ksum) {
    int gid = blockIdx.x * 256 + threadIdx.x;   // 65536 threads x float4
    int idx = gid * 4;
    int bh = idx >> 12, j = idx & 4095;
    const float* p = Kpart + (size_t)(bh * 4) * 4096 + j;
    f32x4 a = *(const f32x4*)p;
    f32x4 bq = *(const f32x4*)(p + 4096);
    f32x4 c = *(const f32x4*)(p + 8192);
    f32x4 d = *(const f32x4*)(p + 12288);
    f32x4 r = a + bq + c + d;
    short4v o;
    #pragma unroll
    for (int k = 0; k < 4; k++) o[k] = (short)f2b(r[k]);
    *(short4v*)((short*)KmatT + idx) = o;
    if (gid < 4096) {
        int bh2 = gid >> 6, e = gid & 63;
        const float* q = kspart + (size_t)(bh2 * 4) * 64 + e;
        ksum[gid] = q[0] + q[64] + q[128] + q[192];
    }
}

// ------- attn_out via MFMA, denominator fused: lane l computes dinv for token s0+l
// (64-MAC f32 dot vs ksum, per-wave LDS stash), then MFMA numerator * dinv. -------
__global__ __launch_bounds__(256) void attn_gemm_k(const bf16t* __restrict__ qf,
                                                   const bf16t* __restrict__ KmatT,
                                                   const float* __restrict__ ksum,
                                                   bf16t* __restrict__ out) {
    __shared__ float dls[4][64];
    int wave = threadIdx.x >> 6, lane = threadIdx.x & 63;
    int wt = blockIdx.x * 4 + wave;      // 1024 wave-tiles: 64 bh x 16 s-tiles
    int bh = wt >> 4, st = wt & 15;
    int b = bh >> 4, h = bh & 15;
    int l16 = lane & 15, quad = lane >> 4;
    int s0 = st * 64;
    // denominator (f32): token s0+lane
    {
        const unsigned short* qr = (const unsigned short*)qf + (size_t)(b * 1024 + s0 + lane) * 1024 + h * 64;
        const float* ks = ksum + (size_t)bh * 64;
        float d = 0.f;
        #pragma unroll
        for (int e = 0; e < 64; e++) d += b2f(qr[e]) * ks[e];
        dls[wave][lane] = frcp(d + 1e-5f);
    }
    const short* Aq = (const short*)qf + (size_t)(b * 1024 + s0 + l16) * 1024 + h * 64;
    const short* Bk = (const short*)KmatT + (size_t)bh * 4096;
    f32x4 acc[4][4] = {};
    #pragma unroll
    for (int k0 = 0; k0 < 64; k0 += 32) {
        int ka = k0 + quad * 8;
        short8 av[4], bv[4];
        #pragma unroll
        for (int i = 0; i < 4; i++) av[i] = *(const short8*)(Aq + (size_t)i * 16 * 1024 + ka);
        #pragma unroll
        for (int j = 0; j < 4; j++) bv[j] = *(const short8*)(Bk + (j * 16 + l16) * 64 + ka);
        #pragma unroll
        for (int i = 0; i < 4; i++)
            #pragma unroll
            for (int j = 0; j < 4; j++)
                acc[i][j] = MFMA16(av[i], bv[j], acc[i][j]);
    }
    #pragma unroll
    for (int i = 0; i < 4; i++) {
        #pragma unroll
        for (int r = 0; r < 4; r++) {
            int trow = i * 16 + quad * 4 + r;
            int t = b * 1024 + s0 + trow;
            float di = dls[wave][trow];
            size_t ob = (size_t)t * 1024 + h * 64;
            #pragma unroll
            for (int j = 0; j < 4; j++)
                out[ob + j * 16 + l16] = __float2bfloat16(acc[i][j][r] * di);
        }
    }
}

// ======================= host =======================
#define LAUNCH_GEMM64(MODE, TCT, TADDT, A_, Bt_, bias_, add_, C_, M_, N_, K_, ldC_)          \
    do {                                                                                     \
        int tiles__ = ((M_) >> 6) * ((N_) >> 7);                                             \
        gemm64_k<MODE, TCT, TADDT><<<tiles__, 256, 0, stream>>>(                             \
            (const bf16t*)(A_), (const bf16t*)(Bt_), (const float*)(bias_),                  \
            (const TADDT*)(add_), (TCT*)(C_), (M_), (N_), (K_), (ldC_));                     \
    } while (0)

#define LAUNCH_GEMM6464(MODE, TCT, TADDT, A_, Bt_, bias_, add_, C_, M_, N_, K_, ldC_)        \
    do {                                                                                     \
        int tiles__ = ((M_) >> 6) * ((N_) >> 6);                                             \
        gemm6464_k<MODE, TCT, TADDT><<<tiles__, 256, 0, stream>>>(                           \
            (const bf16t*)(A_), (const bf16t*)(Bt_), (const float*)(bias_),                  \
            (const TADDT*)(add_), (TCT*)(C_), (M_), (N_), (K_), (ldC_));                     \
    } while (0)

extern "C" void kernel_launch(void* const* d_in, const int* in_sizes, int n_in,
                              void* d_out, int out_size, void* d_ws, size_t ws_size,
                              hipStream_t stream) {
    (void)in_sizes; (void)n_in;
    const float* x    = (const float*)d_in[0];
    const float* ln1g = (const float*)d_in[1];
    const float* ln1b = (const float*)d_in[2];
    const float* ln2g = (const float*)d_in[3];
    const float* ln2b = (const float*)d_in[4];
    const float* Wq  = (const float*)d_in[5];  const float* bq  = (const float*)d_in[6];
    const float* Wk  = (const float*)d_in[7];  const float* bk  = (const float*)d_in[8];
    const float* Wv  = (const float*)d_in[9];  const float* bv  = (const float*)d_in[10];
    const float* Wf  = (const float*)d_in[11]; const float* bWf = (const float*)d_in[12];
    const float* Wr1 = (const float*)d_in[13]; const float* br1 = (const float*)d_in[14];
    const float* Wr2 = (const float*)d_in[15]; const float* br2 = (const float*)d_in[16];
    const float* Wip = (const float*)d_in[17]; const float* bip = (const float*)d_in[18];
    const float* Wtq = (const float*)d_in[19]; const float* btq = (const float*)d_in[20];
    const float* Wtk = (const float*)d_in[21]; const float* btk = (const float*)d_in[22];
    const float* Wtv = (const float*)d_in[23]; const float* btv = (const float*)d_in[24];
    const float* lnpg= (const float*)d_in[25]; const float* lnpb= (const float*)d_in[26];
    const float* Wl1 = (const float*)d_in[27]; const float* bl1 = (const float*)d_in[28];
    const float* Wl2 = (const float*)d_in[29]; const float* bl2 = (const float*)d_in[30];
    const float* Wsp = (const float*)d_in[31]; const float* bsp = (const float*)d_in[32];

    char* ws = (char*)d_ws;
    size_t off = 0;
    auto alloc = [&](size_t bytes) -> char* {
        off = (off + 255) & ~(size_t)255;
        char* p = ws + off;
        off += bytes;
        return p;
    };
    const size_t T = 4096, TS = 131072;
    const size_t MB8 = T * 1024 * 2, MB16 = T * 2048 * 2;
    bf16t* R_xn   = (bf16t*)alloc(MB8);    // xn -> hbuf
    bf16t* R_h1   = (bf16t*)alloc(MB8);    // qf
    bf16t* R_kv0  = (bf16t*)alloc(MB16);   // kv0 -> WfT/Wr1T/Wr2T (tail)
    bf16t* R_inp  = (bf16t*)alloc(MB16);   // inp -> attn_out
    bf16t* R_kk   = (bf16t*)alloc(MB16);   // kk -> slotsO
    bf16t* R_vv   = (bf16t*)alloc(MB16);   // vvT -> res (fp32, 16MB)
    bf16t* R_sl   = (bf16t*)alloc(MB16);   // slots(final) -> r1
    bf16t* Wcat   = (bf16t*)alloc(5120 * 1024 * 2); // concat proj weights
    bf16t* WtkvT = (bf16t*)alloc(128 * 64 * 2);
    bf16t* WtqI = (bf16t*)alloc(64 * 128 * 2);
    bf16t* Wl1T = (bf16t*)alloc(128 * 64 * 2);
    bf16t* Wl2T = (bf16t*)alloc(64 * 128 * 2);
    bf16t* WspT = (bf16t*)alloc(64 * 128 * 2);
    float* bcat = (float*)alloc(5120 * 4);
    float* bcat2 = (float*)alloc(128 * 4);
    bf16t* KmatT = (bf16t*)alloc(64 * 4096 * 2);
    float* ksum = (float*)alloc(64 * 64 * 4);
    float* Kpart = (float*)alloc(256 * 4096 * 4);
    float* kspart = (float*)alloc(256 * 64 * 4);

    if (off > ws_size) {
        fill_k<<<(out_size + 255) / 256, 256, 0, stream>>>((float*)d_out, out_size, 1000.f);
        return;
    }
    float* R_res = (float*)R_vv;   // fp32 res overlays vvT after slot phase
    // tail weight transposes overlay dead kv0 (16 MB >= 10 MB)
    bf16t* WfT  = R_kv0;                        // 1024x1024
    bf16t* Wr1T = R_kv0 + (size_t)1024 * 1024;  // 2048x1024 rows (N=2048,K=1024)
    bf16t* Wr2T = R_kv0 + (size_t)3072 * 1024;  // 1024x2048

    // STAGE1: LN1 + projection-weight transposes + small prep, ONE launch (9223 blocks)
    stage1_k<<<9223, 256, 0, stream>>>(x, ln1g, ln1b, R_xn,
                                       Wk, Wv, Wip, Wq, Wcat,
                                       Wtk, Wtv, Wtq, Wl1, Wl2, Wsp,
                                       bk, bv, bip, bq, btk, btv,
                                       WtkvT, WtqI, Wl1T, Wl2T, WspT, bcat, bcat2);

    // merged projection: kv0, inp, qf in one launch (1280 blocks, XCD-swizzled)
    gemm_proj_k<<<1280, 256, 0, stream>>>(R_xn, Wcat, bcat, R_kv0, R_inp, R_h1);

    // kk = feat(...) and vvT in ONE launch
    gemm_kv_k<<<1024, 256, 0, stream>>>(R_inp, WtkvT, bcat2, R_kk, R_vv);

    // fused slot loop (3 iterations), one wave per token
    slot_all_k<<<1024, 256, 0, stream>>>(R_kv0, R_kk, R_vv, WtqI, btq, lnpg, lnpb,
                                         Wl1T, bl1, Wl2T, bl2, R_sl, 0);

    // slotsO = [kv0|slots]@Wsp + bsp -> R_kk (kk dead)
    gemm_cat_k<<<512, 256, 0, stream>>>(R_kv0, R_sl, WspT, bsp, R_kk, 131072);

    // TAIL MIX: kv_outer (Kpart/kspart) + Wf/Wr1/Wr2 transposes, ONE launch (5376 blocks)
    tail_mix_k<<<5376, 256, 0, stream>>>(R_kk, Kpart, kspart, Wf, Wr1, Wr2, WfT, Wr1T, Wr2T);

    // reduce -> bf16 KmatT + f32 ksum
    kred_k<<<256, 256, 0, stream>>>(Kpart, kspart, KmatT, ksum);

    // attn_out via MFMA (denominator fused) -> R_inp (inp dead)
    attn_gemm_k<<<256, 256, 0, stream>>>(R_h1, KmatT, ksum, R_inp);

    // res = x + attn_out@Wf + bf -> fp32 R_res (vvT dead); 64x64 tiles, BK=64
    LAUNCH_GEMM6464(5, float, float, R_inp, WfT, bWf, x, R_res, 4096, 1024, 1024, 1024);

    // final MLP with residual; Wr1: 64x128 BK=64 (1024 blocks); Wr2: 64x64 BK=64 (1024 blocks)
    ln_kernel<<<4096, 256, 0, stream>>>(R_res, ln2g, ln2b, R_xn);   // hbuf (xn dead)
    LAUNCH_GEMM64(4, bf16t, bf16t, R_xn, Wr1T, br1, nullptr, R_sl, 4096, 2048, 1024, 2048);
    LAUNCH_GEMM6464(5, float, float, R_sl, Wr2T, br2, R_res, (float*)d_out, 4096, 1024, 2048, 1024);
}

// Round 11
// 504.080 us; speedup vs baseline: 1.0167x; 1.0167x over previous
//
#include <hip/hip_runtime.h>
#include <hip/hip_bf16.h>

typedef __hip_bfloat16 bf16t;
typedef short short8 __attribute__((ext_vector_type(8)));
typedef short short4v __attribute__((ext_vector_type(4)));
typedef float f32x4 __attribute__((ext_vector_type(4)));

// B=4, S=1024, D=1024, H=16, E=64, N=32 slots; tokens T=4096; slot-rows TS=131072
// Inputs/outputs are FLOAT32 (per reference). Internal activations bf16 for MFMA.

// fast native exp/rcp for throughput-bound epilogues (outputs round to bf16).
__device__ __forceinline__ float featf(float x) { return x > 0.f ? x + 1.f : __expf(x); }
// libm-exp variant for slot_all_k ONLY: measured 110us vs 122us with __expf there
// (latency-bound kernel; the longer libm sequence + its regalloc footprint wins).
__device__ __forceinline__ float featf_s(float x) { return x > 0.f ? x + 1.f : expf(x); }
__device__ __forceinline__ float frcp(float x) { return __builtin_amdgcn_rcpf(x); }
__device__ __forceinline__ float ldf(const bf16t* p, size_t i) { return __bfloat162float(p[i]); }
__device__ __forceinline__ float ldf(const float* p, size_t i) { return p[i]; }
__device__ __forceinline__ void stf(bf16t* p, size_t i, float v) { p[i] = __float2bfloat16(v); }
__device__ __forceinline__ void stf(float* p, size_t i, float v) { p[i] = v; }
__device__ __forceinline__ float b2f(unsigned short u) {
    unsigned int x = ((unsigned int)u) << 16; float f; __builtin_memcpy(&f, &x, 4); return f;
}
__device__ __forceinline__ unsigned short f2b(float f) {
    bf16t h = __float2bfloat16(f); unsigned short u; __builtin_memcpy(&u, &h, 2); return u;
}
// async global->LDS, 16B per lane; lds dest = wave-uniform base + lane*16
__device__ __forceinline__ void gl_lds16(const short* g, short* l) {
    __builtin_amdgcn_global_load_lds((const __attribute__((address_space(1))) unsigned int*)g,
                                     (__attribute__((address_space(3))) unsigned int*)l, 16, 0, 0);
}
#define MFMA16(a, b, c) __builtin_amdgcn_mfma_f32_16x16x32_bf16((a), (b), (c), 0, 0, 0)

// ---------------- sentinel fill (ws too small diagnostic) ----------------
__global__ __launch_bounds__(256) void fill_k(float* __restrict__ out, int n, float v) {
    int i = blockIdx.x * 256 + threadIdx.x;
    if (i < n) out[i] = v;
}

// ---------------- device helpers shared by merged kernels ----------------
// 32x32 tile transpose + fp32->bf16 (whole block takes same branch; barrier safe)
__device__ __forceinline__ void dev_transpose32(bf16t (*tile)[33], const float* W, bf16t* Wt,
                                                int R, int C, int lb) {
    int tiles_c = C >> 5;
    int c0 = (lb % tiles_c) * 32, r0 = (lb / tiles_c) * 32;
    int tx = threadIdx.x & 31, ty = threadIdx.x >> 5;  // 32 x 8
    #pragma unroll
    for (int i = 0; i < 32; i += 8)
        tile[ty + i][tx] = __float2bfloat16(W[(size_t)(r0 + ty + i) * C + (c0 + tx)]);
    __syncthreads();
    #pragma unroll
    for (int i = 0; i < 32; i += 8)
        Wt[(size_t)(c0 + ty + i) * R + (r0 + tx)] = tile[tx][ty + i];
}

// LayerNorm over D=1024 (fp32 in, bf16 out), one block per token t
__device__ __forceinline__ void dev_ln(float* rs, float* rq,
                                       const float* X, const float* g, const float* b,
                                       bf16t* Y, int t) {
    int tid = threadIdx.x;
    size_t base = (size_t)t * 1024 + tid * 4;
    float v0 = X[base + 0], v1 = X[base + 1], v2 = X[base + 2], v3 = X[base + 3];
    float s = v0 + v1 + v2 + v3;
    float q = v0 * v0 + v1 * v1 + v2 * v2 + v3 * v3;
    for (int o = 32; o > 0; o >>= 1) { s += __shfl_down(s, o); q += __shfl_down(q, o); }
    int wid = tid >> 6, lane = tid & 63;
    if (lane == 0) { rs[wid] = s; rq[wid] = q; }
    __syncthreads();
    float S = rs[0] + rs[1] + rs[2] + rs[3];
    float Q = rq[0] + rq[1] + rq[2] + rq[3];
    float mean = S * (1.f / 1024.f);
    float var = Q * (1.f / 1024.f) - mean * mean;
    float rstd = rsqrtf(var + 1e-5f);
    int c = tid * 4;
    stf(Y, base + 0, (v0 - mean) * rstd * g[c + 0] + b[c + 0]);
    stf(Y, base + 1, (v1 - mean) * rstd * g[c + 1] + b[c + 1]);
    stf(Y, base + 2, (v2 - mean) * rstd * g[c + 2] + b[c + 2]);
    stf(Y, base + 3, (v3 - mean) * rstd * g[c + 3] + b[c + 3]);
}

// ---------------- standalone LN (for LN2; depends on Wf GEMM so can't merge) ----------------
__global__ __launch_bounds__(256) void ln_kernel(const float* __restrict__ X,
                                                 const float* __restrict__ g,
                                                 const float* __restrict__ b,
                                                 bf16t* __restrict__ Y) {
    __shared__ float rs[4], rq[4];
    dev_ln(rs, rq, X, g, b, Y, blockIdx.x);
}

// ======= STAGE1: small_prep + LN1 + projection-weight transposes in ONE launch ===========
// blocks [0,5120): transpose [Wk|Wv|Wip|Wq] -> Wcat; [5120,9216): LN1; [9216,9223): prep.
__global__ __launch_bounds__(256) void stage1_k(const float* __restrict__ x,
                                                const float* __restrict__ ln1g,
                                                const float* __restrict__ ln1b,
                                                bf16t* __restrict__ xn,
                                                const float* __restrict__ Wk,
                                                const float* __restrict__ Wv,
                                                const float* __restrict__ Wip,
                                                const float* __restrict__ Wq,
                                                bf16t* __restrict__ Wcat,
                                                const float* __restrict__ Wtk,
                                                const float* __restrict__ Wtv,
                                                const float* __restrict__ Wtq,
                                                const float* __restrict__ Wl1,
                                                const float* __restrict__ Wl2,
                                                const float* __restrict__ Wsp,
                                                const float* __restrict__ bk,
                                                const float* __restrict__ bv,
                                                const float* __restrict__ bip,
                                                const float* __restrict__ bq,
                                                const float* __restrict__ btk,
                                                const float* __restrict__ btv,
                                                bf16t* __restrict__ WtkvT,
                                                bf16t* __restrict__ WtqI,
                                                bf16t* __restrict__ Wl1T,
                                                bf16t* __restrict__ Wl2T,
                                                bf16t* __restrict__ WspT,
                                                float* __restrict__ bcat,
                                                float* __restrict__ bcat2) {
    __shared__ bf16t tile[32][33];
    __shared__ float rs[4], rq[4];
    int b = blockIdx.x, tid = threadIdx.x;
    if (b < 5120) {
        // 4-job transpose: rows [Wk | Wv | Wip | Wq] into Wcat
        const float* W; bf16t* Wt; int R, C, lb;
        if (b < 1024)      { W = Wk;  Wt = Wcat;                          R = 1024; C = 1024; lb = b; }
        else if (b < 2048) { W = Wv;  Wt = Wcat + (size_t)1024 * 1024;    R = 1024; C = 1024; lb = b - 1024; }
        else if (b < 4096) { W = Wip; Wt = Wcat + (size_t)2048 * 1024;    R = 1024; C = 2048; lb = b - 2048; }
        else               { W = Wq;  Wt = Wcat + (size_t)4096 * 1024;    R = 1024; C = 1024; lb = b - 4096; }
        dev_transpose32(tile, W, Wt, R, C, lb);
    } else if (b < 9216) {
        dev_ln(rs, rq, x, ln1g, ln1b, xn, b - 5120);
    } else {
        int pb = b - 9216;
        if (pb == 0) {
            for (int i = tid; i < 8192; i += 256) {
                int n2 = i >> 6, e = i & 63;
                float v = (n2 < 64) ? Wtk[e * 64 + n2] : Wtv[e * 64 + (n2 - 64)];
                WtkvT[i] = __float2bfloat16(v);
            }
        } else if (pb == 1) {
            for (int i = tid; i < 8192; i += 256) {
                int e = i >> 7, k = i & 127;
                float v = (k < 64) ? Wtq[k * 64 + e] : ((k - 64 == e) ? 1.f : 0.f);
                WtqI[i] = __float2bfloat16(v);
            }
        } else if (pb == 2) {
            for (int i = tid; i < 8192; i += 256) { int n = i >> 6, k = i & 63; Wl1T[i] = __float2bfloat16(Wl1[k * 128 + n]); }
        } else if (pb == 3) {
            for (int i = tid; i < 8192; i += 256) { int n = i >> 7, k = i & 127; Wl2T[i] = __float2bfloat16(Wl2[k * 64 + n]); }
        } else if (pb == 4) {
            for (int i = tid; i < 8192; i += 256) { int n = i >> 7, k = i & 127; WspT[i] = __float2bfloat16(Wsp[k * 64 + n]); }
        } else if (pb == 5) {
            for (int i = tid; i < 5120; i += 256) {
                float v;
                if (i < 1024) v = bk[i];
                else if (i < 2048) v = bv[i - 1024];
                else if (i < 4096) v = bip[i - 2048];
                else v = bq[i - 4096];
                bcat[i] = v;
            }
        } else {
            if (tid < 128) bcat2[tid] = (tid < 64) ? btk[tid] : btv[tid - 64];
        }
    }
}

// ======= 64x128-tile MFMA GEMM, BK=64 (halved barrier count): Wr1 =======================
// Each of 4 waves: 64 rows x 32 cols (acc[4][2]); per K-step 6 gl_lds16 + 16 MFMAs.
// LDS 24KB. MODE 0: v  4: relu(v)  5: v+add. XCD-chunked bid (grid %8==0).
template <int MODE, typename TC, typename TADD>
__global__ __launch_bounds__(256) void gemm64_k(const bf16t* __restrict__ A,
                                                const bf16t* __restrict__ Bt,
                                                const float* __restrict__ bias,
                                                const TADD* __restrict__ add,
                                                TC* __restrict__ C,
                                                int M, int N, int K, int ldC) {
    __shared__ short As[64 * 64];
    __shared__ short Bs[128 * 64];
    int tid = threadIdx.x;
    int wave = tid >> 6, lane = tid & 63;
    int l16 = lane & 15, quad = lane >> 4;
    int tilesM = M >> 6;
    int bid = (blockIdx.x & 7) * (gridDim.x >> 3) + (blockIdx.x >> 3);  // XCD-chunked
    int tm = bid % tilesM;           // column-major: consecutive bids share the B panel
    int tn = bid / tilesM;

    int lrow8 = lane >> 3;           // 0..7 (row within 8-row stripe; 64-col rows = 128B)
    int lseg8 = (lane & 7) * 8;      // 0..56
    const short* Ag  = (const short*)A + (size_t)(tm * 64 + wave * 16 + lrow8) * K + lseg8;
    const short* Ag2 = Ag + (size_t)8 * K;
    const short* Bg  = (const short*)Bt + (size_t)(tn * 128 + wave * 32 + lrow8) * K + lseg8;
    const short* Bg2 = Bg + (size_t)8 * K;
    const short* Bg3 = Bg + (size_t)16 * K;
    const short* Bg4 = Bg + (size_t)24 * K;
    short* Asw  = As + (wave * 16) * 64;
    short* Asw2 = Asw + 8 * 64;
    short* Bsw  = Bs + (wave * 32) * 64;
    short* Bsw2 = Bsw + 8 * 64;
    short* Bsw3 = Bsw + 16 * 64;
    short* Bsw4 = Bsw + 24 * 64;

    f32x4 acc[4][2] = {};
    for (int k0 = 0; k0 < K; k0 += 64) {
        gl_lds16(Ag + k0, Asw);
        gl_lds16(Ag2 + k0, Asw2);
        gl_lds16(Bg + k0, Bsw);
        gl_lds16(Bg2 + k0, Bsw2);
        gl_lds16(Bg3 + k0, Bsw3);
        gl_lds16(Bg4 + k0, Bsw4);
        __syncthreads();
        #pragma unroll
        for (int kk = 0; kk < 2; kk++) {
            short8 av[4], bv[2];
            #pragma unroll
            for (int i = 0; i < 4; i++)
                av[i] = *(const short8*)(As + (i * 16 + l16) * 64 + kk * 32 + quad * 8);
            #pragma unroll
            for (int j = 0; j < 2; j++)
                bv[j] = *(const short8*)(Bs + (wave * 32 + j * 16 + l16) * 64 + kk * 32 + quad * 8);
            #pragma unroll
            for (int i = 0; i < 4; i++)
                #pragma unroll
                for (int j = 0; j < 2; j++)
                    acc[i][j] = MFMA16(av[i], bv[j], acc[i][j]);
        }
        __syncthreads();
    }

    #pragma unroll
    for (int j = 0; j < 2; j++) {
        int col = tn * 128 + wave * 32 + j * 16 + l16;
        float bcol = bias[col];
        #pragma unroll
        for (int i = 0; i < 4; i++) {
            int row0 = tm * 64 + i * 16 + quad * 4;
            #pragma unroll
            for (int r = 0; r < 4; r++) {
                int row = row0 + r;
                float v = acc[i][j][r] + bcol;
                float outv;
                if constexpr (MODE == 0) outv = v;
                else if constexpr (MODE == 4) outv = fmaxf(v, 0.f);
                else if constexpr (MODE == 5) outv = v + ldf(add, (size_t)row * N + col);
                else outv = v;
                stf(C, (size_t)row * ldC + col, outv);
            }
        }
    }
}

// ======= 64x64-tile MFMA GEMM, BK=64: Wf, Wr2 (4 blocks/CU at these shapes) ==============
// Each of 4 waves: 64 rows x 16 cols (acc[4]); per K-step 4 gl_lds16 + 8 MFMAs. LDS 16KB.
template <int MODE, typename TC, typename TADD>
__global__ __launch_bounds__(256) void gemm6464_k(const bf16t* __restrict__ A,
                                                  const bf16t* __restrict__ Bt,
                                                  const float* __restrict__ bias,
                                                  const TADD* __restrict__ add,
                                                  TC* __restrict__ C,
                                                  int M, int N, int K, int ldC) {
    __shared__ short As[64 * 64];
    __shared__ short Bs[64 * 64];
    int tid = threadIdx.x;
    int wave = tid >> 6, lane = tid & 63;
    int l16 = lane & 15, quad = lane >> 4;
    int tilesM = M >> 6;
    int bid = (blockIdx.x & 7) * (gridDim.x >> 3) + (blockIdx.x >> 3);  // XCD-chunked
    int tm = bid % tilesM;           // column-major: consecutive bids share the B panel
    int tn = bid / tilesM;

    int lrow8 = lane >> 3;
    int lseg8 = (lane & 7) * 8;
    const short* Ag  = (const short*)A + (size_t)(tm * 64 + wave * 16 + lrow8) * K + lseg8;
    const short* Ag2 = Ag + (size_t)8 * K;
    const short* Bg  = (const short*)Bt + (size_t)(tn * 64 + wave * 16 + lrow8) * K + lseg8;
    const short* Bg2 = Bg + (size_t)8 * K;
    short* Asw  = As + (wave * 16) * 64;
    short* Asw2 = Asw + 8 * 64;
    short* Bsw  = Bs + (wave * 16) * 64;
    short* Bsw2 = Bsw + 8 * 64;

    f32x4 acc[4] = {};
    for (int k0 = 0; k0 < K; k0 += 64) {
        gl_lds16(Ag + k0, Asw);
        gl_lds16(Ag2 + k0, Asw2);
        gl_lds16(Bg + k0, Bsw);
        gl_lds16(Bg2 + k0, Bsw2);
        __syncthreads();
        #pragma unroll
        for (int kk = 0; kk < 2; kk++) {
            short8 av[4], bv;
            #pragma unroll
            for (int i = 0; i < 4; i++)
                av[i] = *(const short8*)(As + (i * 16 + l16) * 64 + kk * 32 + quad * 8);
            bv = *(const short8*)(Bs + (wave * 16 + l16) * 64 + kk * 32 + quad * 8);
            #pragma unroll
            for (int i = 0; i < 4; i++)
                acc[i] = MFMA16(av[i], bv, acc[i]);
        }
        __syncthreads();
    }

    {
        int col = tn * 64 + wave * 16 + l16;
        float bcol = bias[col];
        #pragma unroll
        for (int i = 0; i < 4; i++) {
            int row0 = tm * 64 + i * 16 + quad * 4;
            #pragma unroll
            for (int r = 0; r < 4; r++) {
                int row = row0 + r;
                float v = acc[i][r] + bcol;
                float outv;
                if constexpr (MODE == 0) outv = v;
                else if constexpr (MODE == 4) outv = fmaxf(v, 0.f);
                else if constexpr (MODE == 5) outv = v + ldf(add, (size_t)row * N + col);
                else outv = v;
                stf(C, (size_t)row * ldC + col, outv);
            }
        }
    }
}

// ======= merged projection GEMM: [xn] @ [Wk|Wv|Wip|Wq]^T (N=5120), split epilogue =========
__global__ __launch_bounds__(256) void gemm_proj_k(const bf16t* __restrict__ A,
                                                   const bf16t* __restrict__ Bt,
                                                   const float* __restrict__ bias,
                                                   bf16t* __restrict__ kv0,
                                                   bf16t* __restrict__ inp,
                                                   bf16t* __restrict__ qf) {
    __shared__ short As[128 * 32];
    __shared__ short Bs[128 * 32];
    const int K = 1024;
    int tid = threadIdx.x;
    int wave = tid >> 6, lane = tid & 63;
    int l16 = lane & 15, quad = lane >> 4;
    int bid = (blockIdx.x & 7) * (gridDim.x >> 3) + (blockIdx.x >> 3);  // XCD-chunked (1280%8==0)
    int tm = bid & 31;
    int tn = bid >> 5;
    int wm = wave >> 1, wn = wave & 1;

    int lrow = lane >> 2;
    int lseg = (lane & 3) * 8;
    const short* Ag = (const short*)A + (size_t)(tm * 128 + wave * 32 + lrow) * K + lseg;
    const short* Ag2 = Ag + (size_t)16 * K;
    const short* Bg = (const short*)Bt + (size_t)(tn * 128 + wave * 32 + lrow) * K + lseg;
    const short* Bg2 = Bg + (size_t)16 * K;
    short* Asw = As + (wave * 32) * 32;
    short* Asw2 = Asw + 16 * 32;
    short* Bsw = Bs + (wave * 32) * 32;
    short* Bsw2 = Bsw + 16 * 32;

    f32x4 acc[4][4] = {};
    for (int k0 = 0; k0 < K; k0 += 32) {
        gl_lds16(Ag + k0, Asw);
        gl_lds16(Ag2 + k0, Asw2);
        gl_lds16(Bg + k0, Bsw);
        gl_lds16(Bg2 + k0, Bsw2);
        __syncthreads();
        short8 av[4], bv[4];
        #pragma unroll
        for (int i = 0; i < 4; i++)
            av[i] = *(const short8*)(As + (wm * 64 + i * 16 + l16) * 32 + quad * 8);
        #pragma unroll
        for (int j = 0; j < 4; j++)
            bv[j] = *(const short8*)(Bs + (wn * 64 + j * 16 + l16) * 32 + quad * 8);
        #pragma unroll
        for (int i = 0; i < 4; i++)
            #pragma unroll
            for (int j = 0; j < 4; j++)
                acc[i][j] = MFMA16(av[i], bv[j], acc[i][j]);
        __syncthreads();
    }

    #pragma unroll
    for (int j = 0; j < 4; j++) {
        int col = tn * 128 + wn * 64 + j * 16 + l16;
        float bcol = bias[col];
        #pragma unroll
        for (int i = 0; i < 4; i++) {
            int row0 = tm * 128 + wm * 64 + i * 16 + quad * 4;
            #pragma unroll
            for (int r = 0; r < 4; r++) {
                int row = row0 + r;
                float v = acc[i][j][r] + bcol;
                if (tn < 16) stf(kv0, (size_t)row * 2048 + col, v);
                else if (tn < 32) stf(inp, (size_t)row * 2048 + (col - 2048), v);
                else stf(qf, (size_t)row * 1024 + (col - 4096), featf(v * 0.125f));
            }
        }
    }
}

// ------- merged kk/vvT GEMM: inp[TS,64] @ [WtkT|WtvT]^T; kk=feat, vvT transpose-store -------
__global__ __launch_bounds__(256) void gemm_kv_k(const bf16t* __restrict__ A,
                                                 const bf16t* __restrict__ Bt,
                                                 const float* __restrict__ bias,
                                                 bf16t* __restrict__ kkO,
                                                 bf16t* __restrict__ vvTO) {
    int wave = threadIdx.x >> 6, lane = threadIdx.x & 63;
    int tile = blockIdx.x * 4 + wave;        // 4096 tiles: 2048 m x 2 n
    int tm = tile >> 1, tn = tile & 1;
    int l16 = lane & 15, quad = lane >> 4;
    f32x4 acc[4][4] = {};
    const short* Ab = (const short*)A + (size_t)(tm * 64 + l16) * 64;
    const short* Bb = (const short*)Bt + (size_t)(tn * 64 + l16) * 64;
    #pragma unroll
    for (int k0 = 0; k0 < 64; k0 += 32) {
        int ka = k0 + quad * 8;
        short8 av[4], bv[4];
        #pragma unroll
        for (int i = 0; i < 4; i++) av[i] = *(const short8*)(Ab + (size_t)i * 16 * 64 + ka);
        #pragma unroll
        for (int j = 0; j < 4; j++) bv[j] = *(const short8*)(Bb + (size_t)j * 16 * 64 + ka);
        #pragma unroll
        for (int i = 0; i < 4; i++)
            #pragma unroll
            for (int j = 0; j < 4; j++)
                acc[i][j] = MFMA16(av[i], bv[j], acc[i][j]);
    }
    #pragma unroll
    for (int j = 0; j < 4; j++) {
        int col = j * 16 + l16;
        float bcol = bias[tn * 64 + col];
        #pragma unroll
        for (int i = 0; i < 4; i++) {
            int row0 = tm * 64 + i * 16 + quad * 4;
            #pragma unroll
            for (int r = 0; r < 4; r++) {
                int row = row0 + r;
                float v = acc[i][j][r] + bcol;
                if (tn == 0) kkO[(size_t)row * 64 + col] = __float2bfloat16(featf(v));
                else stf(vvTO, (size_t)(row >> 5) * 2048 + (size_t)col * 32 + (row & 31), v);
            }
        }
    }
}

// ========== fused slot loop + cat-GEMM epilogue: all 3 iterations, one wave per token ======
// Core loop is the BASELINE version (109-112us @ 124 VGPR; empirical floor over 6 probes):
// libm expf, real fp divides, pitch-72 LDS, shfl-max softmax, no setprio, no bounds cap.
// NEW (R11): epilogue computes slotsO = [kv0|slots]@WspT + bsp directly from LDS slots,
// writing IN PLACE over kk (same rows, per-token ownership; write after last kk read).
// Eliminates the 16MB final-slots store + the entire gemm_cat launch (32MB read/16MB write).
// kkio is NOT __restrict__ (aliases read/write).
__global__ __launch_bounds__(256) void slot_all_k(const bf16t* __restrict__ kv0,
                                                  bf16t* kkio,
                                                  const bf16t* __restrict__ vvT,
                                                  const bf16t* __restrict__ WtqI,
                                                  const float* __restrict__ btq,
                                                  const float* __restrict__ lnpg,
                                                  const float* __restrict__ lnpb,
                                                  const bf16t* __restrict__ Wl1T,
                                                  const float* __restrict__ bl1,
                                                  const bf16t* __restrict__ Wl2T,
                                                  const float* __restrict__ bl2,
                                                  const bf16t* __restrict__ WspT,
                                                  const float* __restrict__ bsp,
                                                  int zoff) {
    __shared__ short slotsS[4][32 * 72];   // per-wave slots [n][e] pitch 72
    __shared__ short scratch[4][32 * 72];  // per-wave qq/attnT/hln/h1-chunk
    int wave = threadIdx.x >> 6, lane = threadIdx.x & 63;
    int l16 = lane & 15, quad = lane >> 4;
    int t = blockIdx.x * 4 + wave;
    short* S = slotsS[wave];
    short* X = scratch[wave];
    size_t tbase = (size_t)t * 2048;

    // slots := kv0 (vectorized copy to LDS, pitch 72)
    {
        const short* src = (const short*)kv0 + tbase;
        #pragma unroll
        for (int p = 0; p < 4; p++) {
            int idx = p * 512 + lane * 8;
            int row = idx >> 6, col = idx & 63;
            *(short8*)(S + row * 72 + col) = *(const short8*)(src + idx);
        }
    }

    #pragma unroll 1
    for (int it = 0; it < 3; it++) {
        int vo = it * zoff;   // zoff==0 at runtime; symbolic per-iteration offset
        // ---- qq = feat(([slots|kv0] @ WtqI^T + btq)/8) -> X [n][e] pitch 72
        f32x4 aq[2][4] = {};
        #pragma unroll
        for (int k0 = 0; k0 < 4; k0++) {
            short8 af[2];
            #pragma unroll
            for (int i = 0; i < 2; i++) {
                if (k0 < 2)
                    af[i] = *(const short8*)(S + (i * 16 + l16) * 72 + k0 * 32 + quad * 8);
                else
                    af[i] = *(const short8*)((const short*)kv0 + tbase + (size_t)((i * 16 + l16) * 64 + (k0 - 2) * 32 + quad * 8 + vo));
            }
            #pragma unroll
            for (int j = 0; j < 4; j++) {
                short8 bf_ = *(const short8*)((const short*)WtqI + (size_t)((j * 16 + l16) * 128 + k0 * 32 + quad * 8 + vo));
                #pragma unroll
                for (int i = 0; i < 2; i++) aq[i][j] = MFMA16(af[i], bf_, aq[i][j]);
            }
        }
        {
            float btqv[4];
            #pragma unroll
            for (int j = 0; j < 4; j++) btqv[j] = btq[j * 16 + l16 + vo];
            #pragma unroll
            for (int i = 0; i < 2; i++)
                #pragma unroll
                for (int j = 0; j < 4; j++)
                    #pragma unroll
                    for (int r = 0; r < 4; r++) {
                        int n = i * 16 + quad * 4 + r, e = j * 16 + l16;
                        X[n * 72 + e] = (short)f2b(featf_s((aq[i][j][r] + btqv[j]) * 0.125f));
                    }
        }
        // ---- logits[w][n] = kk @ qq^T
        f32x4 al[2][2] = {};
        #pragma unroll
        for (int k0 = 0; k0 < 2; k0++) {
            short8 ak[2], bf_[2];
            #pragma unroll
            for (int i = 0; i < 2; i++)
                ak[i] = *(const short8*)((const short*)kkio + tbase + (size_t)((i * 16 + l16) * 64 + k0 * 32 + quad * 8 + vo));
            #pragma unroll
            for (int j = 0; j < 2; j++)
                bf_[j] = *(const short8*)(X + (j * 16 + l16) * 72 + k0 * 32 + quad * 8);
            #pragma unroll
            for (int i = 0; i < 2; i++)
                #pragma unroll
                for (int j = 0; j < 2; j++)
                    al[i][j] = MFMA16(ak[i], bf_[j], al[i][j]);
        }
        // ---- softmax over n (rows w), normalize over w (cols n)
        #pragma unroll
        for (int i = 0; i < 2; i++)
            #pragma unroll
            for (int r = 0; r < 4; r++) {
                float m = fmaxf(al[i][0][r], al[i][1][r]);
                #pragma unroll
                for (int d = 1; d < 16; d <<= 1) m = fmaxf(m, __shfl_xor(m, d));
                float e0 = expf(al[i][0][r] - m), e1 = expf(al[i][1][r] - m);
                float s = e0 + e1;
                #pragma unroll
                for (int d = 1; d < 16; d <<= 1) s += __shfl_xor(s, d);
                float inv = 1.f / s;
                al[i][0][r] = e0 * inv + 1e-6f;
                al[i][1][r] = e1 * inv + 1e-6f;
            }
        #pragma unroll
        for (int j = 0; j < 2; j++) {
            float cs = 0.f;
            #pragma unroll
            for (int i = 0; i < 2; i++)
                #pragma unroll
                for (int r = 0; r < 4; r++) cs += al[i][j][r];
            cs += __shfl_xor(cs, 16);
            cs += __shfl_xor(cs, 32);
            float inv = 1.f / cs;
            #pragma unroll
            for (int i = 0; i < 2; i++)
                #pragma unroll
                for (int r = 0; r < 4; r++) al[i][j][r] *= inv;
        }
        // ---- attn^T -> X [n][w] pitch 40
        #pragma unroll
        for (int i = 0; i < 2; i++)
            #pragma unroll
            for (int j = 0; j < 2; j++)
                #pragma unroll
                for (int r = 0; r < 4; r++) {
                    int w = i * 16 + quad * 4 + r, n = j * 16 + l16;
                    X[n * 40 + w] = (short)f2b(al[i][j][r]);
                }
        // ---- upd[n][e] = attnT @ vvT
        f32x4 au[2][4] = {};
        {
            short8 af[2];
            #pragma unroll
            for (int i = 0; i < 2; i++)
                af[i] = *(const short8*)(X + (i * 16 + l16) * 40 + quad * 8);
            #pragma unroll
            for (int j = 0; j < 4; j++) {
                short8 bf_ = *(const short8*)((const short*)vvT + tbase + (size_t)((j * 16 + l16) * 32 + quad * 8 + vo));
                #pragma unroll
                for (int i = 0; i < 2; i++) au[i][j] = MFMA16(af[i], bf_, au[i][j]);
            }
        }
        // ---- LN over e per row n -> X [n][e] pitch 72
        {
            float lgv[4], lbv[4];
            #pragma unroll
            for (int j = 0; j < 4; j++) { lgv[j] = lnpg[j * 16 + l16 + vo]; lbv[j] = lnpb[j * 16 + l16 + vo]; }
            #pragma unroll
            for (int i = 0; i < 2; i++)
                #pragma unroll
                for (int r = 0; r < 4; r++) {
                    float s1 = 0.f, s2 = 0.f;
                    #pragma unroll
                    for (int j = 0; j < 4; j++) { float u = au[i][j][r]; s1 += u; s2 += u * u; }
                    #pragma unroll
                    for (int d = 1; d < 16; d <<= 1) { s1 += __shfl_xor(s1, d); s2 += __shfl_xor(s2, d); }
                    float mean = s1 * (1.f / 64.f);
                    float var = s2 * (1.f / 64.f) - mean * mean;
                    float rstd = rsqrtf(var + 1e-5f);
                    int n = i * 16 + quad * 4 + r;
                    #pragma unroll
                    for (int j = 0; j < 4; j++)
                        X[n * 72 + j * 16 + l16] = (short)f2b((au[i][j][r] - mean) * rstd * lgv[j] + lbv[j]);
                }
        }
        // ---- MLP (chunked): preload hln A-frags, then 2 chunks of 64 h1-cols
        short8 a1[2][2];
        #pragma unroll
        for (int i = 0; i < 2; i++)
            #pragma unroll
            for (int k0 = 0; k0 < 2; k0++)
                a1[i][k0] = *(const short8*)(X + (i * 16 + l16) * 72 + k0 * 32 + quad * 8);
        f32x4 ac2[2][4] = {};
        #pragma unroll
        for (int c = 0; c < 2; c++) {
            f32x4 ac1[2][4] = {};
            #pragma unroll
            for (int k0 = 0; k0 < 2; k0++)
                #pragma unroll
                for (int j = 0; j < 4; j++) {
                    short8 bf_ = *(const short8*)((const short*)Wl1T + (size_t)(((c * 4 + j) * 16 + l16) * 64 + k0 * 32 + quad * 8 + vo));
                    #pragma unroll
                    for (int i = 0; i < 2; i++) ac1[i][j] = MFMA16(a1[i][k0], bf_, ac1[i][j]);
                }
            {
                float bl1v[4];
                #pragma unroll
                for (int j = 0; j < 4; j++) bl1v[j] = bl1[(c * 4 + j) * 16 + l16 + vo];
                #pragma unroll
                for (int i = 0; i < 2; i++)
                    #pragma unroll
                    for (int j = 0; j < 4; j++)
                        #pragma unroll
                        for (int r = 0; r < 4; r++) {
                            int n = i * 16 + quad * 4 + r;
                            X[n * 72 + j * 16 + l16] = (short)f2b(fmaxf(ac1[i][j][r] + bl1v[j], 0.f));
                        }
            }
            #pragma unroll
            for (int kc = 0; kc < 2; kc++) {
                short8 a2[2];
                #pragma unroll
                for (int i = 0; i < 2; i++)
                    a2[i] = *(const short8*)(X + (i * 16 + l16) * 72 + kc * 32 + quad * 8);
                int k1 = c * 2 + kc;
                #pragma unroll
                for (int j = 0; j < 4; j++) {
                    short8 bf_ = *(const short8*)((const short*)Wl2T + (size_t)((j * 16 + l16) * 128 + k1 * 32 + quad * 8 + vo));
                    #pragma unroll
                    for (int i = 0; i < 2; i++) ac2[i][j] = MFMA16(a2[i], bf_, ac2[i][j]);
                }
            }
        }
        // ---- slot update
        {
            float bl2v[4];
            #pragma unroll
            for (int j = 0; j < 4; j++) bl2v[j] = bl2[j * 16 + l16 + vo];
            #pragma unroll
            for (int i = 0; i < 2; i++)
                #pragma unroll
                for (int j = 0; j < 4; j++)
                    #pragma unroll
                    for (int r = 0; r < 4; r++) {
                        int n = i * 16 + quad * 4 + r, e = j * 16 + l16;
                        float old = b2f((unsigned short)S[n * 72 + e]);
                        S[n * 72 + e] = (short)f2b(old + (ac2[i][j][r] + bl2v[j]) * (1.f / 64.f));
                    }
        }
    }
    // ---- FUSED cat-GEMM epilogue: slotsO[n][j] = [kv0|slots] @ WspT^T + bsp, over kk rows
    {
        f32x4 acS[2][4] = {};
        #pragma unroll
        for (int kc = 0; kc < 4; kc++) {
            short8 af[2];
            #pragma unroll
            for (int i = 0; i < 2; i++) {
                if (kc < 2)
                    af[i] = *(const short8*)((const short*)kv0 + tbase + (size_t)((i * 16 + l16) * 64 + kc * 32 + quad * 8));
                else
                    af[i] = *(const short8*)(S + (i * 16 + l16) * 72 + (kc - 2) * 32 + quad * 8);
            }
            #pragma unroll
            for (int j = 0; j < 4; j++) {
                short8 bf_ = *(const short8*)((const short*)WspT + (size_t)((j * 16 + l16) * 128 + kc * 32 + quad * 8));
                #pragma unroll
                for (int i = 0; i < 2; i++) acS[i][j] = MFMA16(af[i], bf_, acS[i][j]);
            }
        }
        #pragma unroll
        for (int j = 0; j < 4; j++) {
            int col = j * 16 + l16;
            float bcol = bsp[col];
            #pragma unroll
            for (int i = 0; i < 2; i++)
                #pragma unroll
                for (int r = 0; r < 4; r++) {
                    int n = i * 16 + quad * 4 + r;
                    kkio[tbase + (size_t)n * 64 + col] = __float2bfloat16(acS[i][j][r] + bcol);
                }
        }
    }
}

// ======= TAIL MIX: kv_outer (256 blocks, critical path first) + tail weight transposes ====
// Both legal right after slot_all_k: R_kv0 is dead (transposes overlay it), slotsO ready.
__global__ __launch_bounds__(256) void tail_mix_k(const bf16t* __restrict__ slotsO,
                                                  float* __restrict__ Kpart,
                                                  float* __restrict__ kspart,
                                                  const float* __restrict__ Wf,
                                                  const float* __restrict__ Wr1,
                                                  const float* __restrict__ Wr2,
                                                  bf16t* __restrict__ WfT,
                                                  bf16t* __restrict__ Wr1T,
                                                  bf16t* __restrict__ Wr2T) {
    __shared__ short kfT[64 * 72];   // [e][s] pitch 72
    __shared__ short v2T[64 * 72];   // [vj][s] pitch 72
    __shared__ float ksred[8][64];
    __shared__ bf16t tile[32][33];
    int gb = blockIdx.x;
    if (gb >= 256) {
        int lb = gb - 256;
        const float* W; bf16t* Wt; int R, C;
        if (lb < 1024)      { W = Wf;  Wt = WfT;  R = 1024; C = 1024; }
        else if (lb < 3072) { W = Wr1; Wt = Wr1T; R = 1024; C = 2048; lb -= 1024; }
        else                { W = Wr2; Wt = Wr2T; R = 2048; C = 1024; lb -= 3072; }
        dev_transpose32(tile, W, Wt, R, C, lb);
        return;
    }
    // ---- kv_outer: Kpart[vj][e] over a 256-row s-chunk; kspart partial sum_s kf ----
    int blk = gb;
    int bh = blk >> 2, chunk = blk & 3;
    int b = bh >> 4, h = bh & 15;
    int tid = threadIdx.x;
    int wave = tid >> 6, lane = tid & 63;
    int l16 = lane & 15, quad = lane >> 4;
    int m0 = wave * 16;

    int sgrp = tid >> 5;
    int e0 = (tid & 31) * 2;
    float ks0 = 0.f, ks1 = 0.f;
    f32x4 acc[4];
    #pragma unroll
    for (int j = 0; j < 4; j++) acc[j] = (f32x4){0.f, 0.f, 0.f, 0.f};

    for (int tile2 = chunk * 4; tile2 < chunk * 4 + 4; tile2++) {
        #pragma unroll
        for (int p = 0; p < 8; p++) {
            int sl = p * 8 + sgrp;
            size_t row = ((size_t)(b * 1024 + tile2 * 64 + sl)) * 2048;
            unsigned int dk = *(const unsigned int*)((const unsigned short*)slotsO + row + h * 64 + e0);
            float f0 = featf(b2f((unsigned short)(dk & 0xffff)));
            float f1 = featf(b2f((unsigned short)(dk >> 16)));
            ks0 += f0; ks1 += f1;
            kfT[e0 * 72 + sl] = (short)f2b(f0);
            kfT[(e0 + 1) * 72 + sl] = (short)f2b(f1);
            unsigned int dv = *(const unsigned int*)((const unsigned short*)slotsO + row + (16 + h) * 64 + e0);
            v2T[e0 * 72 + sl] = (short)(dv & 0xffff);
            v2T[(e0 + 1) * 72 + sl] = (short)(dv >> 16);
        }
        __syncthreads();
        #pragma unroll
        for (int k2 = 0; k2 < 2; k2++) {
            short8 a = *(const short8*)(v2T + (m0 + l16) * 72 + k2 * 32 + quad * 8);
            #pragma unroll
            for (int j = 0; j < 4; j++) {
                short8 bv = *(const short8*)(kfT + (j * 16 + l16) * 72 + k2 * 32 + quad * 8);
                acc[j] = MFMA16(a, bv, acc[j]);
            }
        }
        __syncthreads();
    }

    float* Km = Kpart + (size_t)blk * 4096;
    #pragma unroll
    for (int j = 0; j < 4; j++)
        #pragma unroll
        for (int r = 0; r < 4; r++)
            Km[(m0 + quad * 4 + r) * 64 + j * 16 + l16] = acc[j][r];

    ksred[sgrp][e0] = ks0;
    ksred[sgrp][e0 + 1] = ks1;
    __syncthreads();
    if (tid < 64) {
        float s = 0.f;
        #pragma unroll
        for (int r = 0; r < 8; r++) s += ksred[r][tid];
        kspart[blk * 64 + tid] = s;
    }
}

// ------- reduce 4 Kpart chunks -> bf16 KmatT[bh][vj][e]; kspart -> f32 ksum ----------------
__global__ __launch_bounds__(256) void kred_k(const float* __restrict__ Kpart,
                                              const float* __restrict__ kspart,
                                              bf16t* __restrict__ KmatT,
                                              float* __restrict__ ksum) {
    int gid = blockIdx.x * 256 + threadIdx.x;   // 65536 threads x float4
    int idx = gid * 4;
    int bh = idx >> 12, j = idx & 4095;
    const float* p = Kpart + (size_t)(bh * 4) * 4096 + j;
    f32x4 a = *(const f32x4*)p;
    f32x4 bq = *(const f32x4*)(p + 4096);
    f32x4 c = *(const f32x4*)(p + 8192);
    f32x4 d = *(const f32x4*)(p + 12288);
    f32x4 r = a + bq + c + d;
    short4v o;
    #pragma unroll
    for (int k = 0; k < 4; k++) o[k] = (short)f2b(r[k]);
    *(short4v*)((short*)KmatT + idx) = o;
    if (gid < 4096) {
        int bh2 = gid >> 6, e = gid & 63;
        const float* q = kspart + (size_t)(bh2 * 4) * 64 + e;
        ksum[gid] = q[0] + q[64] + q[128] + q[192];
    }
}

// ------- attn_out via MFMA, denominator fused: lane l computes dinv for token s0+l
// (64-MAC f32 dot vs ksum, per-wave LDS stash), then MFMA numerator * dinv. -------
__global__ __launch_bounds__(256) void attn_gemm_k(const bf16t* __restrict__ qf,
                                                   const bf16t* __restrict__ KmatT,
                                                   const float* __restrict__ ksum,
                                                   bf16t* __restrict__ out) {
    __shared__ float dls[4][64];
    int wave = threadIdx.x >> 6, lane = threadIdx.x & 63;
    int wt = blockIdx.x * 4 + wave;      // 1024 wave-tiles: 64 bh x 16 s-tiles
    int bh = wt >> 4, st = wt & 15;
    int b = bh >> 4, h = bh & 15;
    int l16 = lane & 15, quad = lane >> 4;
    int s0 = st * 64;
    // denominator (f32): token s0+lane
    {
        const unsigned short* qr = (const unsigned short*)qf + (size_t)(b * 1024 + s0 + lane) * 1024 + h * 64;
        const float* ks = ksum + (size_t)bh * 64;
        float d = 0.f;
        #pragma unroll
        for (int e = 0; e < 64; e++) d += b2f(qr[e]) * ks[e];
        dls[wave][lane] = frcp(d + 1e-5f);
    }
    const short* Aq = (const short*)qf + (size_t)(b * 1024 + s0 + l16) * 1024 + h * 64;
    const short* Bk = (const short*)KmatT + (size_t)bh * 4096;
    f32x4 acc[4][4] = {};
    #pragma unroll
    for (int k0 = 0; k0 < 64; k0 += 32) {
        int ka = k0 + quad * 8;
        short8 av[4], bv[4];
        #pragma unroll
        for (int i = 0; i < 4; i++) av[i] = *(const short8*)(Aq + (size_t)i * 16 * 1024 + ka);
        #pragma unroll
        for (int j = 0; j < 4; j++) bv[j] = *(const short8*)(Bk + (j * 16 + l16) * 64 + ka);
        #pragma unroll
        for (int i = 0; i < 4; i++)
            #pragma unroll
            for (int j = 0; j < 4; j++)
                acc[i][j] = MFMA16(av[i], bv[j], acc[i][j]);
    }
    #pragma unroll
    for (int i = 0; i < 4; i++) {
        #pragma unroll
        for (int r = 0; r < 4; r++) {
            int trow = i * 16 + quad * 4 + r;
            int t = b * 1024 + s0 + trow;
            float di = dls[wave][trow];
            size_t ob = (size_t)t * 1024 + h * 64;
            #pragma unroll
            for (int j = 0; j < 4; j++)
                out[ob + j * 16 + l16] = __float2bfloat16(acc[i][j][r] * di);
        }
    }
}

// ======================= host =======================
#define LAUNCH_GEMM64(MODE, TCT, TADDT, A_, Bt_, bias_, add_, C_, M_, N_, K_, ldC_)          \
    do {                                                                                     \
        int tiles__ = ((M_) >> 6) * ((N_) >> 7);                                             \
        gemm64_k<MODE, TCT, TADDT><<<tiles__, 256, 0, stream>>>(                             \
            (const bf16t*)(A_), (const bf16t*)(Bt_), (const float*)(bias_),                  \
            (const TADDT*)(add_), (TCT*)(C_), (M_), (N_), (K_), (ldC_));                     \
    } while (0)

#define LAUNCH_GEMM6464(MODE, TCT, TADDT, A_, Bt_, bias_, add_, C_, M_, N_, K_, ldC_)        \
    do {                                                                                     \
        int tiles__ = ((M_) >> 6) * ((N_) >> 6);                                             \
        gemm6464_k<MODE, TCT, TADDT><<<tiles__, 256, 0, stream>>>(                           \
            (const bf16t*)(A_), (const bf16t*)(Bt_), (const float*)(bias_),                  \
            (const TADDT*)(add_), (TCT*)(C_), (M_), (N_), (K_), (ldC_));                     \
    } while (0)

extern "C" void kernel_launch(void* const* d_in, const int* in_sizes, int n_in,
                              void* d_out, int out_size, void* d_ws, size_t ws_size,
                              hipStream_t stream) {
    (void)in_sizes; (void)n_in;
    const float* x    = (const float*)d_in[0];
    const float* ln1g = (const float*)d_in[1];
    const float* ln1b = (const float*)d_in[2];
    const float* ln2g = (const float*)d_in[3];
    const float* ln2b = (const float*)d_in[4];
    const float* Wq  = (const float*)d_in[5];  const float* bq  = (const float*)d_in[6];
    const float* Wk  = (const float*)d_in[7];  const float* bk  = (const float*)d_in[8];
    const float* Wv  = (const float*)d_in[9];  const float* bv  = (const float*)d_in[10];
    const float* Wf  = (const float*)d_in[11]; const float* bWf = (const float*)d_in[12];
    const float* Wr1 = (const float*)d_in[13]; const float* br1 = (const float*)d_in[14];
    const float* Wr2 = (const float*)d_in[15]; const float* br2 = (const float*)d_in[16];
    const float* Wip = (const float*)d_in[17]; const float* bip = (const float*)d_in[18];
    const float* Wtq = (const float*)d_in[19]; const float* btq = (const float*)d_in[20];
    const float* Wtk = (const float*)d_in[21]; const float* btk = (const float*)d_in[22];
    const float* Wtv = (const float*)d_in[23]; const float* btv = (const float*)d_in[24];
    const float* lnpg= (const float*)d_in[25]; const float* lnpb= (const float*)d_in[26];
    const float* Wl1 = (const float*)d_in[27]; const float* bl1 = (const float*)d_in[28];
    const float* Wl2 = (const float*)d_in[29]; const float* bl2 = (const float*)d_in[30];
    const float* Wsp = (const float*)d_in[31]; const float* bsp = (const float*)d_in[32];

    char* ws = (char*)d_ws;
    size_t off = 0;
    auto alloc = [&](size_t bytes) -> char* {
        off = (off + 255) & ~(size_t)255;
        char* p = ws + off;
        off += bytes;
        return p;
    };
    const size_t T = 4096, TS = 131072;
    const size_t MB8 = T * 1024 * 2, MB16 = T * 2048 * 2;
    bf16t* R_xn   = (bf16t*)alloc(MB8);    // xn -> hbuf
    bf16t* R_h1   = (bf16t*)alloc(MB8);    // qf
    bf16t* R_kv0  = (bf16t*)alloc(MB16);   // kv0 -> WfT/Wr1T/Wr2T (tail)
    bf16t* R_inp  = (bf16t*)alloc(MB16);   // inp -> attn_out
    bf16t* R_kk   = (bf16t*)alloc(MB16);   // kk -> slotsO (in-place in slot_all_k)
    bf16t* R_vv   = (bf16t*)alloc(MB16);   // vvT -> res (fp32, 16MB)
    bf16t* R_sl   = (bf16t*)alloc(MB16);   // r1 (MLP intermediate)
    bf16t* Wcat   = (bf16t*)alloc(5120 * 1024 * 2); // concat proj weights
    bf16t* WtkvT = (bf16t*)alloc(128 * 64 * 2);
    bf16t* WtqI = (bf16t*)alloc(64 * 128 * 2);
    bf16t* Wl1T = (bf16t*)alloc(128 * 64 * 2);
    bf16t* Wl2T = (bf16t*)alloc(64 * 128 * 2);
    bf16t* WspT = (bf16t*)alloc(64 * 128 * 2);
    float* bcat = (float*)alloc(5120 * 4);
    float* bcat2 = (float*)alloc(128 * 4);
    bf16t* KmatT = (bf16t*)alloc(64 * 4096 * 2);
    float* ksum = (float*)alloc(64 * 64 * 4);
    float* Kpart = (float*)alloc(256 * 4096 * 4);
    float* kspart = (float*)alloc(256 * 64 * 4);

    if (off > ws_size) {
        fill_k<<<(out_size + 255) / 256, 256, 0, stream>>>((float*)d_out, out_size, 1000.f);
        return;
    }
    float* R_res = (float*)R_vv;   // fp32 res overlays vvT after slot phase
    // tail weight transposes overlay dead kv0 (16 MB >= 10 MB)
    bf16t* WfT  = R_kv0;                        // 1024x1024
    bf16t* Wr1T = R_kv0 + (size_t)1024 * 1024;  // 2048x1024 rows (N=2048,K=1024)
    bf16t* Wr2T = R_kv0 + (size_t)3072 * 1024;  // 1024x2048

    // STAGE1: LN1 + projection-weight transposes + small prep, ONE launch (9223 blocks)
    stage1_k<<<9223, 256, 0, stream>>>(x, ln1g, ln1b, R_xn,
                                       Wk, Wv, Wip, Wq, Wcat,
                                       Wtk, Wtv, Wtq, Wl1, Wl2, Wsp,
                                       bk, bv, bip, bq, btk, btv,
                                       WtkvT, WtqI, Wl1T, Wl2T, WspT, bcat, bcat2);

    // merged projection: kv0, inp, qf in one launch (1280 blocks, XCD-swizzled)
    gemm_proj_k<<<1280, 256, 0, stream>>>(R_xn, Wcat, bcat, R_kv0, R_inp, R_h1);

    // kk = feat(...) and vvT in ONE launch
    gemm_kv_k<<<1024, 256, 0, stream>>>(R_inp, WtkvT, bcat2, R_kk, R_vv);

    // fused slot loop (3 iterations) + cat-GEMM epilogue: slotsO written in place over kk
    slot_all_k<<<1024, 256, 0, stream>>>(R_kv0, R_kk, R_vv, WtqI, btq, lnpg, lnpb,
                                         Wl1T, bl1, Wl2T, bl2, WspT, bsp, 0);

    // TAIL MIX: kv_outer (Kpart/kspart) + Wf/Wr1/Wr2 transposes, ONE launch (5376 blocks)
    tail_mix_k<<<5376, 256, 0, stream>>>(R_kk, Kpart, kspart, Wf, Wr1, Wr2, WfT, Wr1T, Wr2T);

    // reduce -> bf16 KmatT + f32 ksum
    kred_k<<<256, 256, 0, stream>>>(Kpart, kspart, KmatT, ksum);

    // attn_out via MFMA (denominator fused) -> R_inp (inp dead)
    attn_gemm_k<<<256, 256, 0, stream>>>(R_h1, KmatT, ksum, R_inp);

    // res = x + attn_out@Wf + bf -> fp32 R_res (vvT dead); 64x64 tiles, BK=64
    LAUNCH_GEMM6464(5, float, float, R_inp, WfT, bWf, x, R_res, 4096, 1024, 1024, 1024);

    // final MLP with residual; Wr1: 64x128 BK=64 (1024 blocks); Wr2: 64x64 BK=64 (1024 blocks)
    ln_kernel<<<4096, 256, 0, stream>>>(R_res, ln2g, ln2b, R_xn);   // hbuf (xn dead)
    LAUNCH_GEMM64(4, bf16t, bf16t, R_xn, Wr1T, br1, nullptr, R_sl, 4096, 2048, 1024, 2048);
    LAUNCH_GEMM6464(5, float, float, R_sl, Wr2T, br2, R_res, (float*)d_out, 4096, 1024, 2048, 1024);
}